// Round 1
// baseline (975.101 us; speedup 1.0000x reference)
//
#include <hip/hip_runtime.h>
#include <math.h>

#define D_ 512
#define M_ 256
#define T_ 128
#define B_ 8
#define TOPK_ 8
#define NH_ 2
#define BT_ (B_*T_)

__device__ __forceinline__ float wred(float v){
#pragma unroll
  for (int m = 1; m < 64; m <<= 1) v += __shfl_xor(v, m, 64);
  return v;
}

// ---------------------------------------------------------------------------
// A1: addresses — z = h_t @ W^T (32 dims), softmax per 16-group, kron outer
// product to 256, top-8. One 64-thread block per (b,t).
// ---------------------------------------------------------------------------
__global__ __launch_bounds__(64) void addr_kernel(
    const float* __restrict__ h, const float* __restrict__ Wk,
    const float* __restrict__ Wq, const float* __restrict__ ltw,
    const float* __restrict__ ltr, int* __restrict__ widxb,
    float* __restrict__ wwb, int* __restrict__ ridxb)
{
  const int bt = blockIdx.x;
  const int tid = threadIdx.x;
  __shared__ float z_s[64], p_s[64];
  __shared__ float addr_s[2][256];

  const float* hrow = h + (size_t)bt * D_;
  const float* wrow = (tid < 32) ? (Wk + (size_t)tid * D_)
                                 : (Wq + (size_t)(tid - 32) * D_);
  float dot = 0.f;
  for (int d = 0; d < D_; d += 4){
    float4 hv = *(const float4*)&hrow[d];
    float4 wv = *(const float4*)&wrow[d];
    dot += hv.x*wv.x + hv.y*wv.y + hv.z*wv.z + hv.w*wv.w;
  }
  z_s[tid] = dot;
  __syncthreads();

  float tau = (tid < 32) ? expf(ltw[0]) : expf(ltr[0]);
  int base = tid & ~15;
  float mx = -1e30f;
  for (int k = 0; k < 16; ++k) mx = fmaxf(mx, z_s[base+k]);
  float e = expf((z_s[tid] - mx) / tau);
  float sum = 0.f;
  for (int k = 0; k < 16; ++k) sum += expf((z_s[base+k] - mx) / tau);
  p_s[tid] = e / sum;
  __syncthreads();

  for (int k = 0; k < 4; ++k){
    int x = tid*4 + k;
    addr_s[0][x] = p_s[x>>4] * p_s[16 + (x&15)];
    addr_s[1][x] = p_s[32 + (x>>4)] * p_s[48 + (x&15)];
  }
  __syncthreads();

  if (tid < 2){
    float* a = addr_s[tid];
    for (int s = 0; s < TOPK_; ++s){
      float bv = -1.f; int bi = 0;
      for (int i = 0; i < 256; ++i){ if (a[i] > bv){ bv = a[i]; bi = i; } }
      a[bi] = -2.f;
      if (tid == 0){ widxb[bt*TOPK_+s] = bi; wwb[bt*TOPK_+s] = bv; }
      else         { ridxb[bt*TOPK_+s] = bi; }
    }
  }
}

// ---------------------------------------------------------------------------
// A2/C: fp32 NT GEMM  C[n,d] = sum_k A[n,k] * W[d,k],  M=1024 N=512 K=512.
// 64x64 tile, 256 threads, 4x4 register tile. mode 1: C = sigmoid(acc)*C_prev.
// Batched over grid.z via pointer table.
// ---------------------------------------------------------------------------
struct GemmPtrs { const float* W[6]; float* C[6]; };

__global__ __launch_bounds__(256) void gemm_nt(
    const float* __restrict__ A, GemmPtrs p, int mode)
{
  const float* W = p.W[blockIdx.z];
  float* C = p.C[blockIdx.z];
  const int n0 = blockIdx.x * 64;
  const int m0 = blockIdx.y * 64;
  const int tid = threadIdx.x;
  __shared__ __align__(16) float As[16][68];
  __shared__ __align__(16) float Bs[16][68];
  const int r  = tid >> 2;
  const int c4 = (tid & 3) << 2;
  const int tx4 = (tid & 15) << 2;
  const int ty4 = (tid >> 4) << 2;
  float acc[4][4] = {{0.f}};

  for (int kc = 0; kc < 512; kc += 16){
    float4 av = *(const float4*)&A[(size_t)(m0+r)*512 + kc + c4];
    float4 wv = *(const float4*)&W[(size_t)(n0+r)*512 + kc + c4];
    __syncthreads();
    As[c4+0][r]=av.x; As[c4+1][r]=av.y; As[c4+2][r]=av.z; As[c4+3][r]=av.w;
    Bs[c4+0][r]=wv.x; Bs[c4+1][r]=wv.y; Bs[c4+2][r]=wv.z; Bs[c4+3][r]=wv.w;
    __syncthreads();
#pragma unroll
    for (int k = 0; k < 16; ++k){
      float4 a  = *(const float4*)&As[k][ty4];
      float4 bq = *(const float4*)&Bs[k][tx4];
      acc[0][0]+=a.x*bq.x; acc[0][1]+=a.x*bq.y; acc[0][2]+=a.x*bq.z; acc[0][3]+=a.x*bq.w;
      acc[1][0]+=a.y*bq.x; acc[1][1]+=a.y*bq.y; acc[1][2]+=a.y*bq.z; acc[1][3]+=a.y*bq.w;
      acc[2][0]+=a.z*bq.x; acc[2][1]+=a.z*bq.y; acc[2][2]+=a.z*bq.z; acc[2][3]+=a.z*bq.w;
      acc[3][0]+=a.w*bq.x; acc[3][1]+=a.w*bq.y; acc[3][2]+=a.w*bq.z; acc[3][3]+=a.w*bq.w;
    }
  }
#pragma unroll
  for (int i = 0; i < 4; ++i){
    float* cp = &C[(size_t)(m0+ty4+i)*512 + n0 + tx4];
    float4 cv; cv.x=acc[i][0]; cv.y=acc[i][1]; cv.z=acc[i][2]; cv.w=acc[i][3];
    if (mode == 1){
      float4 pv = *(const float4*)cp;
      cv.x = pv.x / (1.f + expf(-cv.x));
      cv.y = pv.y / (1.f + expf(-cv.y));
      cv.z = pv.z / (1.f + expf(-cv.z));
      cv.w = pv.w / (1.f + expf(-cv.w));
    }
    *(float4*)cp = cv;
  }
}

// ---------------------------------------------------------------------------
// A3: elementwise per (j, b, t): silu, row-norm -> k_hat, kv products, beta.
// In-place over the GEMM outputs. 256 threads, 2 elems each.
// ---------------------------------------------------------------------------
__global__ __launch_bounds__(256) void ew_kernel(
    float* __restrict__ khat, float* __restrict__ kvk, float* __restrict__ kvv,
    float* __restrict__ betab, const float* __restrict__ h,
    const float* __restrict__ hh_bw, const float* __restrict__ hh_bb)
{
  const int blk = blockIdx.x;
  const int j  = blk >> 10;
  const int bt = blk & 1023;
  const int tid = threadIdx.x;
  float* kp  = khat + (size_t)j*BT_*D_ + (size_t)bt*D_;
  float* vkp = kvk  + (size_t)j*BT_*D_ + (size_t)bt*D_;
  float* vvp = kvv  + (size_t)j*BT_*D_ + (size_t)bt*D_;
  const float* hp  = h + (size_t)bt*D_;
  const float* bwp = hh_bw + (size_t)j*D_;

  float s[2]; float nrm = 0.f, bd = 0.f;
#pragma unroll
  for (int q = 0; q < 2; ++q){
    int d = tid + q*256;
    float x = kp[d];
    float sv = x / (1.f + expf(-x));   // silu
    s[q] = sv; nrm += sv*sv; bd += hp[d]*bwp[d];
  }
  nrm = wred(nrm); bd = wred(bd);
  __shared__ float rb[8];
  int wid = tid >> 6, lane = tid & 63;
  if (lane == 0){ rb[wid] = nrm; rb[4+wid] = bd; }
  __syncthreads();
  float ns = rb[0]+rb[1]+rb[2]+rb[3];
  float bs = rb[4]+rb[5]+rb[6]+rb[7];
  float inv = 1.f / fmaxf(sqrtf(ns), 1e-12f);
#pragma unroll
  for (int q = 0; q < 2; ++q){
    int d = tid + q*256;
    float sv = s[q];
    kp[d]  = sv * inv;       // k_hat
    vkp[d] = sv * vkp[d];    // k_j ⊙ v_kj
    vvp[d] = sv * vvp[d];    // k_j ⊙ v_vj
  }
  if (tid == 0) betab[(size_t)j*BT_ + bt] = 2.f / (1.f + expf(-(bs + hh_bb[j])));
}

// ---------------------------------------------------------------------------
// B: sequential scan. One 1024-thread block per batch (independent).
// Waves 0-7: K slot i in registers; waves 8-15: V slot i.
// State lives in d_out's K_s/V_s regions; zK/zV live in LDS for the whole scan.
// ---------------------------------------------------------------------------
__global__ __launch_bounds__(1024) void scan_kernel(
    float* __restrict__ Ks, float* __restrict__ Vs,
    const float* __restrict__ zK0, const float* __restrict__ zV0,
    const float* __restrict__ khat, const float* __restrict__ kvkb,
    const float* __restrict__ kvvb, const float* __restrict__ betab,
    const int* __restrict__ widxb, const float* __restrict__ wwb,
    const int* __restrict__ ridxb, const float* __restrict__ h,
    const float* __restrict__ gammap, float* __restrict__ readout,
    float* __restrict__ o_zK, float* __restrict__ o_zV,
    float* __restrict__ o_widx, float* __restrict__ o_ridx)
{
  __shared__ __align__(16) float kh_s[2][D_];
  __shared__ __align__(16) float kvk_s[2][D_];
  __shared__ __align__(16) float kvv_s[2][D_];
  __shared__ __align__(16) float ht_s[D_];
  __shared__ __align__(16) float Vr_s[TOPK_][D_];
  __shared__ float zK_s[M_], zV_s[M_];
  __shared__ float rel_s[TOPK_], coef_s[TOPK_];
  __shared__ int ridx_s[TOPK_];

  const int b = blockIdx.x;
  const int tid = threadIdx.x;
  const int wid = tid >> 6, lane = tid & 63;
  const int l4 = lane * 4;
  const float sp = log1pf(expf(gammap[0]));      // softplus(gamma)
  const float scale = 1.0f / sqrtf((float)D_);

  if (tid < M_){ zK_s[tid] = zK0[b*M_+tid]; zV_s[tid] = zV0[b*M_+tid]; }

  float* Ksb = Ks + (size_t)b*M_*D_;
  float* Vsb = Vs + (size_t)b*M_*D_;
  const bool isK = (wid < 8);
  const int slot = isK ? wid : wid - 8;
  float* Sb = isK ? Ksb : Vsb;

  __syncthreads();

  for (int t = 0; t < T_; ++t){
    const int bt = b*T_ + t;

    // ---- phase 1: all loads + scalar state updates ----
    if (tid < 896){
      int grp = tid >> 7;            // 7 groups of 128 threads (2 waves each)
      int q = (tid & 127) * 4;
      const float* src; float* dst;
      switch (grp){
        case 0: src = &khat[0*BT_*D_ + (size_t)bt*D_ + q]; dst = &kh_s[0][q]; break;
        case 1: src = &khat[1*BT_*D_ + (size_t)bt*D_ + q]; dst = &kh_s[1][q]; break;
        case 2: src = &kvkb[0*BT_*D_ + (size_t)bt*D_ + q]; dst = &kvk_s[0][q]; break;
        case 3: src = &kvkb[1*BT_*D_ + (size_t)bt*D_ + q]; dst = &kvk_s[1][q]; break;
        case 4: src = &kvvb[0*BT_*D_ + (size_t)bt*D_ + q]; dst = &kvv_s[0][q]; break;
        case 5: src = &kvvb[1*BT_*D_ + (size_t)bt*D_ + q]; dst = &kvv_s[1][q]; break;
        default: src = &h[(size_t)bt*D_ + q];              dst = &ht_s[q];     break;
      }
      *(float4*)dst = *(const float4*)src;
    }
    // gather write slots into registers (with decay applied)
    int   mi  = widxb[bt*TOPK_ + slot];
    float wv  = wwb [bt*TOPK_ + slot];
    float dec = powf(1.0f - wv, sp);
    float4 a0 = *(const float4*)&Sb[(size_t)mi*D_ + l4];
    float4 a1 = *(const float4*)&Sb[(size_t)mi*D_ + 256 + l4];
    a0.x*=dec; a0.y*=dec; a0.z*=dec; a0.w*=dec;
    a1.x*=dec; a1.y*=dec; a1.z*=dec; a1.w*=dec;
    float be0 = betab[0*BT_ + bt];
    float be1 = betab[1*BT_ + bt];
    // zK/zV updates + read-index staging (wave 15 lanes)
    if (tid >= 960 && tid < 960+TOPK_){
      int i = tid-960; int m = widxb[bt*TOPK_+i]; float w = wwb[bt*TOPK_+i];
      zK_s[m] = powf(1.0f-w, sp)*zK_s[m] + w;
    } else if (tid >= 968 && tid < 968+TOPK_){
      int i = tid-968; int m = widxb[bt*TOPK_+i]; float w = wwb[bt*TOPK_+i];
      zV_s[m] = powf(1.0f-w, sp)*zV_s[m] + w;
    } else if (tid >= 976 && tid < 976+TOPK_){
      int i = tid-976; ridx_s[i] = ridxb[bt*TOPK_+i];
    }
    __syncthreads();

    // ---- phase 2: NH delta-rule updates, entirely within-wave ----
#pragma unroll
    for (int j = 0; j < NH_; ++j){
      const float* khj = kh_s[j];
      const float* kvj = isK ? kvk_s[j] : kvv_s[j];
      float bj = (j == 0) ? be0 : be1;
      float4 k0 = *(const float4*)&khj[l4];
      float4 k1 = *(const float4*)&khj[256 + l4];
      float pd = a0.x*k0.x + a0.y*k0.y + a0.z*k0.z + a0.w*k0.w
               + a1.x*k1.x + a1.y*k1.y + a1.z*k1.z + a1.w*k1.w;
      float dot = wred(pd);
      float4 v0 = *(const float4*)&kvj[l4];
      float4 v1 = *(const float4*)&kvj[256 + l4];
      a0.x = a0.x - bj*k0.x*dot + bj*v0.x;
      a0.y = a0.y - bj*k0.y*dot + bj*v0.y;
      a0.z = a0.z - bj*k0.z*dot + bj*v0.z;
      a0.w = a0.w - bj*k0.w*dot + bj*v0.w;
      a1.x = a1.x - bj*k1.x*dot + bj*v1.x;
      a1.y = a1.y - bj*k1.y*dot + bj*v1.y;
      a1.z = a1.z - bj*k1.z*dot + bj*v1.z;
      a1.w = a1.w - bj*k1.w*dot + bj*v1.w;
    }
    // scatter updated slots back to global state
    *(float4*)&Sb[(size_t)mi*D_ + l4] = a0;
    *(float4*)&Sb[(size_t)mi*D_ + 256 + l4] = a1;
    __syncthreads();

    // ---- phase 3: read gather (post-scatter state is current) ----
    {
      int ri = ridx_s[slot];
      if (isK){
        float4 r0 = *(const float4*)&Ksb[(size_t)ri*D_ + l4];
        float4 r1 = *(const float4*)&Ksb[(size_t)ri*D_ + 256 + l4];
        float4 h0 = *(const float4*)&ht_s[l4];
        float4 h1 = *(const float4*)&ht_s[256 + l4];
        float pd = r0.x*h0.x + r0.y*h0.y + r0.z*h0.z + r0.w*h0.w
                 + r1.x*h1.x + r1.y*h1.y + r1.z*h1.z + r1.w*h1.w;
        float dt = wred(pd);
        if (lane == 0) rel_s[slot] = dt / zK_s[ri] * scale;
      } else {
        float4 r0 = *(const float4*)&Vsb[(size_t)ri*D_ + l4];
        float4 r1 = *(const float4*)&Vsb[(size_t)ri*D_ + 256 + l4];
        *(float4*)&Vr_s[slot][l4] = r0;
        *(float4*)&Vr_s[slot][256 + l4] = r1;
      }
    }
    __syncthreads();

    // ---- phase 4: softmax over 8 read slots ----
    if (tid == 0){
      float mx = -1e30f;
#pragma unroll
      for (int i = 0; i < TOPK_; ++i) mx = fmaxf(mx, rel_s[i]);
      float e[TOPK_]; float s = 0.f;
#pragma unroll
      for (int i = 0; i < TOPK_; ++i){ e[i] = expf(rel_s[i]-mx); s += e[i]; }
#pragma unroll
      for (int i = 0; i < TOPK_; ++i) coef_s[i] = e[i] / s / zV_s[ridx_s[i]];
    }
    __syncthreads();

    // ---- phase 5: readout ----
    if (tid < D_){
      float r = 0.f;
#pragma unroll
      for (int i = 0; i < TOPK_; ++i) r += coef_s[i] * Vr_s[i][tid];
      readout[(size_t)bt*D_ + tid] = r;
    }
    __syncthreads();
  }

  // epilogue: final zK/zV and last-step indices (as float32)
  if (tid < M_){ o_zK[b*M_+tid] = zK_s[tid]; o_zV[b*M_+tid] = zV_s[tid]; }
  if (tid < TOPK_){
    o_widx[b*TOPK_+tid] = (float)widxb[(b*T_ + T_-1)*TOPK_ + tid];
    o_ridx[b*TOPK_+tid] = (float)ridxb[(b*T_ + T_-1)*TOPK_ + tid];
  }
}

// ---------------------------------------------------------------------------
extern "C" void kernel_launch(void* const* d_in, const int* in_sizes, int n_in,
                              void* d_out, int out_size, void* d_ws, size_t ws_size,
                              hipStream_t stream)
{
  (void)in_sizes; (void)n_in; (void)out_size; (void)ws_size;
  const float* h       = (const float*)d_in[0];
  const float* K_slots = (const float*)d_in[1];
  const float* V_slots = (const float*)d_in[2];
  const float* z_K     = (const float*)d_in[3];
  const float* z_V     = (const float*)d_in[4];
  const float* W_k     = (const float*)d_in[5];
  const float* W_q     = (const float*)d_in[6];
  const float* ltw     = (const float*)d_in[7];
  const float* ltr     = (const float*)d_in[8];
  const float* hh_k    = (const float*)d_in[9];
  const float* hh_vk   = (const float*)d_in[10];
  const float* hh_vv   = (const float*)d_in[11];
  const float* hh_bw   = (const float*)d_in[12];
  const float* hh_bb   = (const float*)d_in[13];
  const float* gamma   = (const float*)d_in[14];
  const float* W_out   = (const float*)d_in[15];
  const float* W_gate  = (const float*)d_in[16];

  float* out    = (float*)d_out;
  float* o_outs = out;                 // (B,T,D)   524288
  float* o_Ks   = out + 524288;        // (B,M,D)  1048576
  float* o_Vs   = out + 1572864;       // (B,M,D)  1048576
  float* o_zK   = out + 2621440;       // (B,M)       2048
  float* o_zV   = out + 2623488;       // (B,M)       2048
  float* o_widx = out + 2625536;       // (B,8)         64
  float* o_ridx = out + 2625600;       // (B,8)         64

  float* ws    = (float*)d_ws;
  float* khat  = ws;                         // 2 * BT * D
  float* kvk   = ws + 2*(size_t)BT_*D_;      // 2 * BT * D
  float* kvv   = kvk + 2*(size_t)BT_*D_;     // 2 * BT * D
  float* rdo   = kvv + 2*(size_t)BT_*D_;     // BT * D
  float* betab = rdo + (size_t)BT_*D_;       // 2 * BT
  float* wwb   = betab + 2*BT_;              // BT * 8
  int*   widxb = (int*)(wwb + BT_*TOPK_);    // BT * 8
  int*   ridxb = widxb + BT_*TOPK_;          // BT * 8

  // seed state in output buffers (graph-capture-safe D2D copies)
  hipMemcpyAsync(o_Ks, K_slots, sizeof(float)*(size_t)B_*M_*D_,
                 hipMemcpyDeviceToDevice, stream);
  hipMemcpyAsync(o_Vs, V_slots, sizeof(float)*(size_t)B_*M_*D_,
                 hipMemcpyDeviceToDevice, stream);

  // A1: addresses + top-k
  addr_kernel<<<BT_, 64, 0, stream>>>(h, W_k, W_q, ltw, ltr, widxb, wwb, ridxb);

  // A2: six 1024x512x512 NT GEMMs (hh_k / hh_vk / hh_vv for both heads)
  GemmPtrs p{};
  p.W[0] = hh_k;           p.C[0] = khat;
  p.W[1] = hh_k + 262144;  p.C[1] = khat + (size_t)BT_*D_;
  p.W[2] = hh_vk;          p.C[2] = kvk;
  p.W[3] = hh_vk + 262144; p.C[3] = kvk + (size_t)BT_*D_;
  p.W[4] = hh_vv;          p.C[4] = kvv;
  p.W[5] = hh_vv + 262144; p.C[5] = kvv + (size_t)BT_*D_;
  gemm_nt<<<dim3(8,16,6), 256, 0, stream>>>(h, p, 0);

  // A3: silu/norm/kv-products/beta
  ew_kernel<<<2*BT_, 256, 0, stream>>>(khat, kvk, kvv, betab, h, hh_bw, hh_bb);

  // B: sequential scan (one block per batch)
  scan_kernel<<<B_, 1024, 0, stream>>>(o_Ks, o_Vs, z_K, z_V, khat, kvk, kvv,
                                       betab, widxb, wwb, ridxb, h, gamma, rdo,
                                       o_zK, o_zV, o_widx, o_ridx);

  // C: out = sigmoid(h@W_gate.T) * (readout@W_out.T)
  GemmPtrs p2{}; p2.W[0] = W_out;  p2.C[0] = o_outs;
  gemm_nt<<<dim3(8,16,1), 256, 0, stream>>>(rdo, p2, 0);
  GemmPtrs p3{}; p3.W[0] = W_gate; p3.C[0] = o_outs;
  gemm_nt<<<dim3(8,16,1), 256, 0, stream>>>(h, p3, 1);
}

// Round 2
// 800.265 us; speedup vs baseline: 1.2185x; 1.2185x over previous
//
#include <hip/hip_runtime.h>
#include <math.h>

#define D_ 512
#define M_ 256
#define T_ 128
#define B_ 8
#define TOPK_ 8
#define NH_ 2
#define BT_ (B_*T_)

__device__ __forceinline__ float wred(float v){
#pragma unroll
  for (int m = 1; m < 64; m <<= 1) v += __shfl_xor(v, m, 64);
  return v;
}

// ---------------------------------------------------------------------------
// A1: addresses — z = h_t @ W^T (32 dims), softmax per 16-group, kron outer
// product to 256, top-8, plus precomputed decay (1-w)^softplus(gamma).
// ---------------------------------------------------------------------------
__global__ __launch_bounds__(64) void addr_kernel(
    const float* __restrict__ h, const float* __restrict__ Wk,
    const float* __restrict__ Wq, const float* __restrict__ ltw,
    const float* __restrict__ ltr, const float* __restrict__ gammap,
    int* __restrict__ widxb, float* __restrict__ wwb,
    float* __restrict__ decb, int* __restrict__ ridxb)
{
  const int bt = blockIdx.x;
  const int tid = threadIdx.x;
  __shared__ float z_s[64], p_s[64];
  __shared__ float addr_s[2][256];

  const float* hrow = h + (size_t)bt * D_;
  const float* wrow = (tid < 32) ? (Wk + (size_t)tid * D_)
                                 : (Wq + (size_t)(tid - 32) * D_);
  float dot = 0.f;
  for (int d = 0; d < D_; d += 4){
    float4 hv = *(const float4*)&hrow[d];
    float4 wv = *(const float4*)&wrow[d];
    dot += hv.x*wv.x + hv.y*wv.y + hv.z*wv.z + hv.w*wv.w;
  }
  z_s[tid] = dot;
  __syncthreads();

  float tau = (tid < 32) ? expf(ltw[0]) : expf(ltr[0]);
  int base = tid & ~15;
  float mx = -1e30f;
  for (int k = 0; k < 16; ++k) mx = fmaxf(mx, z_s[base+k]);
  float e = expf((z_s[tid] - mx) / tau);
  float sum = 0.f;
  for (int k = 0; k < 16; ++k) sum += expf((z_s[base+k] - mx) / tau);
  p_s[tid] = e / sum;
  __syncthreads();

  for (int k = 0; k < 4; ++k){
    int x = tid*4 + k;
    addr_s[0][x] = p_s[x>>4] * p_s[16 + (x&15)];
    addr_s[1][x] = p_s[32 + (x>>4)] * p_s[48 + (x&15)];
  }
  __syncthreads();

  if (tid < 2){
    float sp = log1pf(expf(gammap[0]));
    float* a = addr_s[tid];
    for (int s = 0; s < TOPK_; ++s){
      float bv = -1.f; int bi = 0;
      for (int i = 0; i < 256; ++i){ if (a[i] > bv){ bv = a[i]; bi = i; } }
      a[bi] = -2.f;
      if (tid == 0){
        widxb[bt*TOPK_+s] = bi; wwb[bt*TOPK_+s] = bv;
        decb[bt*TOPK_+s] = powf(1.0f - bv, sp);
      } else {
        ridxb[bt*TOPK_+s] = bi;
      }
    }
  }
}

// ---------------------------------------------------------------------------
// A2: fp32 NT GEMM  C[n,d] = sum_k A[n,k]*W[d,k], M=1024 N=512 K=512.
// 64x64 tile, 256 threads, 4x4 register tile. Batched over grid.z.
// ---------------------------------------------------------------------------
struct GemmPtrs { const float* W[6]; float* C[6]; };

__global__ __launch_bounds__(256) void gemm_nt(
    const float* __restrict__ A, GemmPtrs p)
{
  const float* W = p.W[blockIdx.z];
  float* C = p.C[blockIdx.z];
  const int n0 = blockIdx.x * 64;
  const int m0 = blockIdx.y * 64;
  const int tid = threadIdx.x;
  __shared__ __align__(16) float As[16][68];
  __shared__ __align__(16) float Bs[16][68];
  const int r  = tid >> 2;
  const int c4 = (tid & 3) << 2;
  const int tx4 = (tid & 15) << 2;
  const int ty4 = (tid >> 4) << 2;
  float acc[4][4] = {{0.f}};

  for (int kc = 0; kc < 512; kc += 16){
    float4 av = *(const float4*)&A[(size_t)(m0+r)*512 + kc + c4];
    float4 wv = *(const float4*)&W[(size_t)(n0+r)*512 + kc + c4];
    __syncthreads();
    As[c4+0][r]=av.x; As[c4+1][r]=av.y; As[c4+2][r]=av.z; As[c4+3][r]=av.w;
    Bs[c4+0][r]=wv.x; Bs[c4+1][r]=wv.y; Bs[c4+2][r]=wv.z; Bs[c4+3][r]=wv.w;
    __syncthreads();
#pragma unroll
    for (int k = 0; k < 16; ++k){
      float4 a  = *(const float4*)&As[k][ty4];
      float4 bq = *(const float4*)&Bs[k][tx4];
      acc[0][0]+=a.x*bq.x; acc[0][1]+=a.x*bq.y; acc[0][2]+=a.x*bq.z; acc[0][3]+=a.x*bq.w;
      acc[1][0]+=a.y*bq.x; acc[1][1]+=a.y*bq.y; acc[1][2]+=a.y*bq.z; acc[1][3]+=a.y*bq.w;
      acc[2][0]+=a.z*bq.x; acc[2][1]+=a.z*bq.y; acc[2][2]+=a.z*bq.z; acc[2][3]+=a.z*bq.w;
      acc[3][0]+=a.w*bq.x; acc[3][1]+=a.w*bq.y; acc[3][2]+=a.w*bq.z; acc[3][3]+=a.w*bq.w;
    }
  }
#pragma unroll
  for (int i = 0; i < 4; ++i){
    float4 cv; cv.x=acc[i][0]; cv.y=acc[i][1]; cv.z=acc[i][2]; cv.w=acc[i][3];
    *(float4*)&C[(size_t)(m0+ty4+i)*512 + n0 + tx4] = cv;
  }
}

// ---------------------------------------------------------------------------
// C: fused out = sigmoid(h@Wg.T) * (rdo@Wo.T). Dual accumulators.
// ---------------------------------------------------------------------------
__global__ __launch_bounds__(256) void gemm_out(
    const float* __restrict__ h, const float* __restrict__ rdo,
    const float* __restrict__ Wg, const float* __restrict__ Wo,
    float* __restrict__ C)
{
  const int n0 = blockIdx.x * 64;
  const int m0 = blockIdx.y * 64;
  const int tid = threadIdx.x;
  __shared__ __align__(16) float Ag[16][68];
  __shared__ __align__(16) float Ao[16][68];
  __shared__ __align__(16) float Bg[16][68];
  __shared__ __align__(16) float Bo[16][68];
  const int r  = tid >> 2;
  const int c4 = (tid & 3) << 2;
  const int tx4 = (tid & 15) << 2;
  const int ty4 = (tid >> 4) << 2;
  float accg[4][4] = {{0.f}};
  float acco[4][4] = {{0.f}};

  for (int kc = 0; kc < 512; kc += 16){
    float4 a1 = *(const float4*)&h  [(size_t)(m0+r)*512 + kc + c4];
    float4 a2 = *(const float4*)&rdo[(size_t)(m0+r)*512 + kc + c4];
    float4 w1 = *(const float4*)&Wg [(size_t)(n0+r)*512 + kc + c4];
    float4 w2 = *(const float4*)&Wo [(size_t)(n0+r)*512 + kc + c4];
    __syncthreads();
    Ag[c4+0][r]=a1.x; Ag[c4+1][r]=a1.y; Ag[c4+2][r]=a1.z; Ag[c4+3][r]=a1.w;
    Ao[c4+0][r]=a2.x; Ao[c4+1][r]=a2.y; Ao[c4+2][r]=a2.z; Ao[c4+3][r]=a2.w;
    Bg[c4+0][r]=w1.x; Bg[c4+1][r]=w1.y; Bg[c4+2][r]=w1.z; Bg[c4+3][r]=w1.w;
    Bo[c4+0][r]=w2.x; Bo[c4+1][r]=w2.y; Bo[c4+2][r]=w2.z; Bo[c4+3][r]=w2.w;
    __syncthreads();
#pragma unroll
    for (int k = 0; k < 16; ++k){
      float4 ag = *(const float4*)&Ag[k][ty4];
      float4 ao = *(const float4*)&Ao[k][ty4];
      float4 bg = *(const float4*)&Bg[k][tx4];
      float4 bo = *(const float4*)&Bo[k][tx4];
      accg[0][0]+=ag.x*bg.x; accg[0][1]+=ag.x*bg.y; accg[0][2]+=ag.x*bg.z; accg[0][3]+=ag.x*bg.w;
      accg[1][0]+=ag.y*bg.x; accg[1][1]+=ag.y*bg.y; accg[1][2]+=ag.y*bg.z; accg[1][3]+=ag.y*bg.w;
      accg[2][0]+=ag.z*bg.x; accg[2][1]+=ag.z*bg.y; accg[2][2]+=ag.z*bg.z; accg[2][3]+=ag.z*bg.w;
      accg[3][0]+=ag.w*bg.x; accg[3][1]+=ag.w*bg.y; accg[3][2]+=ag.w*bg.z; accg[3][3]+=ag.w*bg.w;
      acco[0][0]+=ao.x*bo.x; acco[0][1]+=ao.x*bo.y; acco[0][2]+=ao.x*bo.z; acco[0][3]+=ao.x*bo.w;
      acco[1][0]+=ao.y*bo.x; acco[1][1]+=ao.y*bo.y; acco[1][2]+=ao.y*bo.z; acco[1][3]+=ao.y*bo.w;
      acco[2][0]+=ao.z*bo.x; acco[2][1]+=ao.z*bo.y; acco[2][2]+=ao.z*bo.z; acco[2][3]+=ao.z*bo.w;
      acco[3][0]+=ao.w*bo.x; acco[3][1]+=ao.w*bo.y; acco[3][2]+=ao.w*bo.z; acco[3][3]+=ao.w*bo.w;
    }
  }
#pragma unroll
  for (int i = 0; i < 4; ++i){
    float4 cv;
    cv.x = acco[i][0] / (1.f + expf(-accg[i][0]));
    cv.y = acco[i][1] / (1.f + expf(-accg[i][1]));
    cv.z = acco[i][2] / (1.f + expf(-accg[i][2]));
    cv.w = acco[i][3] / (1.f + expf(-accg[i][3]));
    *(float4*)&C[(size_t)(m0+ty4+i)*512 + n0 + tx4] = cv;
  }
}

// ---------------------------------------------------------------------------
// A3: elementwise per (j, b, t): silu, row-norm -> k_hat, kv products, beta.
// ---------------------------------------------------------------------------
__global__ __launch_bounds__(256) void ew_kernel(
    float* __restrict__ khat, float* __restrict__ kvk, float* __restrict__ kvv,
    float* __restrict__ betab, const float* __restrict__ h,
    const float* __restrict__ hh_bw, const float* __restrict__ hh_bb)
{
  const int blk = blockIdx.x;
  const int j  = blk >> 10;
  const int bt = blk & 1023;
  const int tid = threadIdx.x;
  float* kp  = khat + (size_t)j*BT_*D_ + (size_t)bt*D_;
  float* vkp = kvk  + (size_t)j*BT_*D_ + (size_t)bt*D_;
  float* vvp = kvv  + (size_t)j*BT_*D_ + (size_t)bt*D_;
  const float* hp  = h + (size_t)bt*D_;
  const float* bwp = hh_bw + (size_t)j*D_;

  float s[2]; float nrm = 0.f, bd = 0.f;
#pragma unroll
  for (int q = 0; q < 2; ++q){
    int d = tid + q*256;
    float x = kp[d];
    float sv = x / (1.f + expf(-x));   // silu
    s[q] = sv; nrm += sv*sv; bd += hp[d]*bwp[d];
  }
  nrm = wred(nrm); bd = wred(bd);
  __shared__ float rb[8];
  int wid = tid >> 6, lane = tid & 63;
  if (lane == 0){ rb[wid] = nrm; rb[4+wid] = bd; }
  __syncthreads();
  float ns = rb[0]+rb[1]+rb[2]+rb[3];
  float bs = rb[4]+rb[5]+rb[6]+rb[7];
  float inv = 1.f / fmaxf(sqrtf(ns), 1e-12f);
#pragma unroll
  for (int q = 0; q < 2; ++q){
    int d = tid + q*256;
    float sv = s[q];
    kp[d]  = sv * inv;       // k_hat
    vkp[d] = sv * vkp[d];    // k_j ⊙ v_kj
    vvp[d] = sv * vvp[d];    // k_j ⊙ v_vj
  }
  if (tid == 0) betab[(size_t)j*BT_ + bt] = 2.f / (1.f + expf(-(bs + hh_bb[j])));
}

// ---------------------------------------------------------------------------
// B: sequential scan v2. 512 threads (8 waves) per batch; wave s owns write
// slot s for BOTH K and V. 3 barriers/step; double-buffered LDS staging;
// LDS forwarding for read-slots that are in this step's write set (so the
// global scatter's visibility is only needed at the NEXT step's gather).
// ---------------------------------------------------------------------------
__global__ __launch_bounds__(512) void scan_kernel(
    float* __restrict__ Ks, float* __restrict__ Vs,
    const float* __restrict__ zK0, const float* __restrict__ zV0,
    const float* __restrict__ khat, const float* __restrict__ kvkb,
    const float* __restrict__ kvvb, const float* __restrict__ betab,
    const int* __restrict__ widxb, const float* __restrict__ wwb,
    const float* __restrict__ decb, const int* __restrict__ ridxb,
    const float* __restrict__ h, float* __restrict__ readout,
    float* __restrict__ o_zK, float* __restrict__ o_zV,
    float* __restrict__ o_widx, float* __restrict__ o_ridx)
{
  // staged vectors: [kh0,kh1,kvk0,kvk1,kvv0,kvv1,ht] x 512 floats, x2 buffers
  __shared__ __align__(16) float buf[2][7*D_];
  __shared__ __align__(16) float fwdK[TOPK_][D_];
  __shared__ __align__(16) float fwdV[TOPK_][D_];
  __shared__ __align__(16) float Vr_s[TOPK_][D_];
  __shared__ float zK_s[M_], zV_s[M_];
  __shared__ int   widx_sb[2][TOPK_]; __shared__ float ww_sb[2][TOPK_];
  __shared__ float dec_sb[2][TOPK_];  __shared__ int   ridx_sb[2][TOPK_];
  __shared__ float be_sb[2][NH_];
  __shared__ float rel_s[TOPK_], zvr_s[TOPK_];

  const int b = blockIdx.x;
  const int tid = threadIdx.x;
  const int s = tid >> 6;            // wave id == slot id
  const int lane = tid & 63;
  const int l4 = lane * 4;
  const float scale = 1.0f / sqrtf((float)D_);

  float* Ksb = Ks + (size_t)b*M_*D_;
  float* Vsb = Vs + (size_t)b*M_*D_;

  // per-thread prefetch mapping: flat float4 index f -> (vector v, offset o)
  // vector order: kh j0, kh j1, kvk j0, kvk j1, kvv j0, kvv j1, h
  const float* vbase[7] = { khat, khat + (size_t)BT_*D_,
                            kvkb, kvkb + (size_t)BT_*D_,
                            kvvb, kvvb + (size_t)BT_*D_, h };
  int f0 = tid, f1 = tid + 448;
  const float* pb0 = vbase[f0>>7]; int po0 = (f0&127)*4; int pd0 = (f0>>7)*D_ + po0;
  const float* pb1 = (tid<448) ? vbase[f1>>7] : vbase[0];
  int po1 = (f1&127)*4; int pd1 = (f1>>7)*D_ + po1;

  // ---- prologue: stage step 0 into buffer 0; init z ----
  {
    int bt0 = b*T_;
    if (tid < 448){
      *(float4*)&buf[0][pd0] = *(const float4*)(pb0 + (size_t)bt0*D_ + po0);
      *(float4*)&buf[0][pd1] = *(const float4*)(pb1 + (size_t)bt0*D_ + po1);
    } else if (tid < 482){
      int g = tid - 448;
      if      (g < 8)  widx_sb[0][g]    = widxb[bt0*TOPK_+g];
      else if (g < 16) ww_sb[0][g-8]    = wwb [bt0*TOPK_+g-8];
      else if (g < 24) dec_sb[0][g-16]  = decb[bt0*TOPK_+g-16];
      else if (g < 32) ridx_sb[0][g-24] = ridxb[bt0*TOPK_+g-24];
      else             be_sb[0][g-32]   = betab[(size_t)(g-32)*BT_ + bt0];
    }
    if (tid < M_){ zK_s[tid] = zK0[b*M_+tid]; zV_s[tid] = zV0[b*M_+tid]; }
  }
  __syncthreads();

  for (int t = 0; t < T_; ++t){
    const int bt  = b*T_ + t;
    const int cur = t & 1, nxt = cur ^ 1;
    const int btn = bt + ((t+1 < T_) ? 1 : 0);

    // ---- phase 1: issue prefetch; gather+decay; NH delta updates; forward ----
    float4 pv0, pv1; int pint = 0; float pflt = 0.f; int g = tid - 448;
    if (tid < 448){
      pv0 = *(const float4*)(pb0 + (size_t)btn*D_ + po0);
      pv1 = *(const float4*)(pb1 + (size_t)btn*D_ + po1);
    } else if (tid < 482){
      if      (g < 8)  pint = widxb[btn*TOPK_+g];
      else if (g < 16) pflt = wwb [btn*TOPK_+g-8];
      else if (g < 24) pflt = decb[btn*TOPK_+g-16];
      else if (g < 32) pint = ridxb[btn*TOPK_+g-24];
      else             pflt = betab[(size_t)(g-32)*BT_ + btn];
    }

    const int   mi  = widx_sb[cur][s];
    const float dec = dec_sb[cur][s];
    float4 K0 = *(const float4*)&Ksb[(size_t)mi*D_ + l4];
    float4 K1 = *(const float4*)&Ksb[(size_t)mi*D_ + 256 + l4];
    float4 V0 = *(const float4*)&Vsb[(size_t)mi*D_ + l4];
    float4 V1 = *(const float4*)&Vsb[(size_t)mi*D_ + 256 + l4];
    K0.x*=dec; K0.y*=dec; K0.z*=dec; K0.w*=dec;
    K1.x*=dec; K1.y*=dec; K1.z*=dec; K1.w*=dec;
    V0.x*=dec; V0.y*=dec; V0.z*=dec; V0.w*=dec;
    V1.x*=dec; V1.y*=dec; V1.z*=dec; V1.w*=dec;

#pragma unroll
    for (int j = 0; j < NH_; ++j){
      const float* khj = &buf[cur][j*D_];
      const float* vkj = &buf[cur][(2+j)*D_];
      const float* vvj = &buf[cur][(4+j)*D_];
      const float bj = be_sb[cur][j];
      float4 k0 = *(const float4*)&khj[l4];
      float4 k1 = *(const float4*)&khj[256 + l4];
      float dK = K0.x*k0.x + K0.y*k0.y + K0.z*k0.z + K0.w*k0.w
               + K1.x*k1.x + K1.y*k1.y + K1.z*k1.z + K1.w*k1.w;
      float dV = V0.x*k0.x + V0.y*k0.y + V0.z*k0.z + V0.w*k0.w
               + V1.x*k1.x + V1.y*k1.y + V1.z*k1.z + V1.w*k1.w;
#pragma unroll
      for (int m = 1; m < 64; m <<= 1){
        dK += __shfl_xor(dK, m, 64);
        dV += __shfl_xor(dV, m, 64);
      }
      float4 a0 = *(const float4*)&vkj[l4];
      float4 a1 = *(const float4*)&vkj[256 + l4];
      float4 b0 = *(const float4*)&vvj[l4];
      float4 b1 = *(const float4*)&vvj[256 + l4];
      K0.x += bj*(a0.x - k0.x*dK); K0.y += bj*(a0.y - k0.y*dK);
      K0.z += bj*(a0.z - k0.z*dK); K0.w += bj*(a0.w - k0.w*dK);
      K1.x += bj*(a1.x - k1.x*dK); K1.y += bj*(a1.y - k1.y*dK);
      K1.z += bj*(a1.z - k1.z*dK); K1.w += bj*(a1.w - k1.w*dK);
      V0.x += bj*(b0.x - k0.x*dV); V0.y += bj*(b0.y - k0.y*dV);
      V0.z += bj*(b0.z - k0.z*dV); V0.w += bj*(b0.w - k0.w*dV);
      V1.x += bj*(b1.x - k1.x*dV); V1.y += bj*(b1.y - k1.y*dV);
      V1.z += bj*(b1.z - k1.z*dV); V1.w += bj*(b1.w - k1.w*dV);
    }

    // forward updated rows via LDS (read phase can then ignore scatter timing)
    *(float4*)&fwdK[s][l4]       = K0;
    *(float4*)&fwdK[s][256 + l4] = K1;
    *(float4*)&fwdV[s][l4]       = V0;
    *(float4*)&fwdV[s][256 + l4] = V1;

    // stage prefetched data into the other buffer
    if (tid < 448){
      *(float4*)&buf[nxt][pd0] = pv0;
      *(float4*)&buf[nxt][pd1] = pv1;
    } else if (tid < 482){
      if      (g < 8)  widx_sb[nxt][g]    = pint;
      else if (g < 16) ww_sb[nxt][g-8]    = pflt;
      else if (g < 24) dec_sb[nxt][g-16]  = pflt;
      else if (g < 32) ridx_sb[nxt][g-24] = pint;
      else             be_sb[nxt][g-32]   = pflt;
    } else if (tid < 490){            // zK updates (distinct top-k indices)
      int i = tid - 482; int m = widx_sb[cur][i];
      zK_s[m] = dec_sb[cur][i]*zK_s[m] + ww_sb[cur][i];
    } else if (tid < 498){            // zV updates
      int i = tid - 490; int m = widx_sb[cur][i];
      zV_s[m] = dec_sb[cur][i]*zV_s[m] + ww_sb[cur][i];
    }
    __syncthreads();   // barrier 1: z updated, fwd rows + next stage visible

    // ---- phase 2: scatter (drains at barrier 2, overlapped) + read gather ----
    *(float4*)&Ksb[(size_t)mi*D_ + l4]       = K0;
    *(float4*)&Ksb[(size_t)mi*D_ + 256 + l4] = K1;
    *(float4*)&Vsb[(size_t)mi*D_ + l4]       = V0;
    *(float4*)&Vsb[(size_t)mi*D_ + 256 + l4] = V1;

    {
      const int ri = ridx_sb[cur][s];       // wave-uniform
      int fm = -1;
#pragma unroll
      for (int w = 0; w < TOPK_; ++w) if (widx_sb[cur][w] == ri) fm = w;
      float4 r0, r1, u0, u1;
      if (fm >= 0){                          // wave-uniform branch
        r0 = *(const float4*)&fwdK[fm][l4];
        r1 = *(const float4*)&fwdK[fm][256 + l4];
        u0 = *(const float4*)&fwdV[fm][l4];
        u1 = *(const float4*)&fwdV[fm][256 + l4];
      } else {
        r0 = *(const float4*)&Ksb[(size_t)ri*D_ + l4];
        r1 = *(const float4*)&Ksb[(size_t)ri*D_ + 256 + l4];
        u0 = *(const float4*)&Vsb[(size_t)ri*D_ + l4];
        u1 = *(const float4*)&Vsb[(size_t)ri*D_ + 256 + l4];
      }
      const float* ht = &buf[cur][6*D_];
      float4 h0 = *(const float4*)&ht[l4];
      float4 h1 = *(const float4*)&ht[256 + l4];
      float pd = r0.x*h0.x + r0.y*h0.y + r0.z*h0.z + r0.w*h0.w
               + r1.x*h1.x + r1.y*h1.y + r1.z*h1.z + r1.w*h1.w;
      float dt = wred(pd);
      *(float4*)&Vr_s[s][l4]       = u0;
      *(float4*)&Vr_s[s][256 + l4] = u1;
      if (lane == 0){
        rel_s[s] = dt * scale / zK_s[ri];
        zvr_s[s] = zV_s[ri];
      }
    }
    __syncthreads();   // barrier 2

    // ---- phase 3: redundant per-thread softmax + readout ----
    {
      float rl[TOPK_];
#pragma unroll
      for (int i = 0; i < TOPK_; ++i) rl[i] = rel_s[i];
      float mx = rl[0];
#pragma unroll
      for (int i = 1; i < TOPK_; ++i) mx = fmaxf(mx, rl[i]);
      float e[TOPK_]; float sm = 0.f;
#pragma unroll
      for (int i = 0; i < TOPK_; ++i){ e[i] = expf(rl[i]-mx); sm += e[i]; }
      float inv = 1.f / sm;
      float r = 0.f;
#pragma unroll
      for (int i = 0; i < TOPK_; ++i) r += (e[i]*inv/zvr_s[i]) * Vr_s[i][tid];
      readout[(size_t)bt*D_ + tid] = r;
    }
    __syncthreads();   // barrier 3 (protects Vr_s/rel_s/z for next step)
  }

  // epilogue: final zK/zV and last-step indices (as float32)
  if (tid < M_){ o_zK[b*M_+tid] = zK_s[tid]; o_zV[b*M_+tid] = zV_s[tid]; }
  if (tid < TOPK_){
    o_widx[b*TOPK_+tid] = (float)widxb[(b*T_ + T_-1)*TOPK_ + tid];
    o_ridx[b*TOPK_+tid] = (float)ridxb[(b*T_ + T_-1)*TOPK_ + tid];
  }
}

// ---------------------------------------------------------------------------
extern "C" void kernel_launch(void* const* d_in, const int* in_sizes, int n_in,
                              void* d_out, int out_size, void* d_ws, size_t ws_size,
                              hipStream_t stream)
{
  (void)in_sizes; (void)n_in; (void)out_size; (void)ws_size;
  const float* h       = (const float*)d_in[0];
  const float* K_slots = (const float*)d_in[1];
  const float* V_slots = (const float*)d_in[2];
  const float* z_K     = (const float*)d_in[3];
  const float* z_V     = (const float*)d_in[4];
  const float* W_k     = (const float*)d_in[5];
  const float* W_q     = (const float*)d_in[6];
  const float* ltw     = (const float*)d_in[7];
  const float* ltr     = (const float*)d_in[8];
  const float* hh_k    = (const float*)d_in[9];
  const float* hh_vk   = (const float*)d_in[10];
  const float* hh_vv   = (const float*)d_in[11];
  const float* hh_bw   = (const float*)d_in[12];
  const float* hh_bb   = (const float*)d_in[13];
  const float* gamma   = (const float*)d_in[14];
  const float* W_out   = (const float*)d_in[15];
  const float* W_gate  = (const float*)d_in[16];

  float* out    = (float*)d_out;
  float* o_outs = out;                 // (B,T,D)   524288
  float* o_Ks   = out + 524288;        // (B,M,D)  1048576
  float* o_Vs   = out + 1572864;       // (B,M,D)  1048576
  float* o_zK   = out + 2621440;       // (B,M)       2048
  float* o_zV   = out + 2623488;       // (B,M)       2048
  float* o_widx = out + 2625536;       // (B,8)         64
  float* o_ridx = out + 2625600;       // (B,8)         64

  float* ws    = (float*)d_ws;
  float* khat  = ws;                         // 2 * BT * D
  float* kvk   = ws + 2*(size_t)BT_*D_;      // 2 * BT * D
  float* kvv   = kvk + 2*(size_t)BT_*D_;     // 2 * BT * D
  float* rdo   = kvv + 2*(size_t)BT_*D_;     // BT * D
  float* betab = rdo + (size_t)BT_*D_;       // 2 * BT
  float* wwb   = betab + 2*BT_;              // BT * 8
  float* decb  = wwb + BT_*TOPK_;            // BT * 8
  int*   widxb = (int*)(decb + BT_*TOPK_);   // BT * 8
  int*   ridxb = widxb + BT_*TOPK_;          // BT * 8

  hipMemcpyAsync(o_Ks, K_slots, sizeof(float)*(size_t)B_*M_*D_,
                 hipMemcpyDeviceToDevice, stream);
  hipMemcpyAsync(o_Vs, V_slots, sizeof(float)*(size_t)B_*M_*D_,
                 hipMemcpyDeviceToDevice, stream);

  addr_kernel<<<BT_, 64, 0, stream>>>(h, W_k, W_q, ltw, ltr, gamma,
                                      widxb, wwb, decb, ridxb);

  GemmPtrs p{};
  p.W[0] = hh_k;           p.C[0] = khat;
  p.W[1] = hh_k + 262144;  p.C[1] = khat + (size_t)BT_*D_;
  p.W[2] = hh_vk;          p.C[2] = kvk;
  p.W[3] = hh_vk + 262144; p.C[3] = kvk + (size_t)BT_*D_;
  p.W[4] = hh_vv;          p.C[4] = kvv;
  p.W[5] = hh_vv + 262144; p.C[5] = kvv + (size_t)BT_*D_;
  gemm_nt<<<dim3(8,16,6), 256, 0, stream>>>(h, p);

  ew_kernel<<<2*BT_, 256, 0, stream>>>(khat, kvk, kvv, betab, h, hh_bw, hh_bb);

  scan_kernel<<<B_, 512, 0, stream>>>(o_Ks, o_Vs, z_K, z_V, khat, kvk, kvv,
                                      betab, widxb, wwb, decb, ridxb, h, rdo,
                                      o_zK, o_zV, o_widx, o_ridx);

  gemm_out<<<dim3(8,16), 256, 0, stream>>>(h, rdo, W_gate, W_out, o_outs);
}

// Round 3
// 699.573 us; speedup vs baseline: 1.3939x; 1.1439x over previous
//
#include <hip/hip_runtime.h>
#include <math.h>

#define D_ 512
#define M_ 256
#define T_ 128
#define B_ 8
#define TOPK_ 8
#define NH_ 2
#define BT_ (B_*T_)

__device__ __forceinline__ float wred(float v){
#pragma unroll
  for (int m = 1; m < 64; m <<= 1) v += __shfl_xor(v, m, 64);
  return v;
}
__device__ __forceinline__ float4 ld4(const float* p){ return *(const float4*)p; }
__device__ __forceinline__ void st4(float* p, float4 v){ *(float4*)p = v; }
__device__ __forceinline__ float dot4(float4 a, float4 b){
  return a.x*b.x + a.y*b.y + a.z*b.z + a.w*b.w;
}
__device__ __forceinline__ float4 scl4(float4 a, float s){
  a.x*=s; a.y*=s; a.z*=s; a.w*=s; return a;
}
__device__ __forceinline__ float4 upd4(float4 r, float4 u0, float4 u1,
                                       float4 k0, float4 k1,
                                       float b0, float b1, float p0, float p1){
  r.x += b0*u0.x + b1*u1.x - p0*k0.x - p1*k1.x;
  r.y += b0*u0.y + b1*u1.y - p0*k0.y - p1*k1.y;
  r.z += b0*u0.z + b1*u1.z - p0*k0.z - p1*k1.z;
  r.w += b0*u0.w + b1*u1.w - p0*k0.w - p1*k1.w;
  return r;
}

// ---------------------------------------------------------------------------
// A1: addresses + parallel top-8. One wave per (b,t); lanes 0-31 handle the
// write stream, 32-63 the read stream. Wave-argmax butterfly per round.
// ---------------------------------------------------------------------------
__global__ __launch_bounds__(64) void addr_kernel(
    const float* __restrict__ h, const float* __restrict__ Wk,
    const float* __restrict__ Wq, const float* __restrict__ ltw,
    const float* __restrict__ ltr, const float* __restrict__ gammap,
    int* __restrict__ widxb, float* __restrict__ wwb,
    float* __restrict__ decb, int* __restrict__ ridxb)
{
  const int bt = blockIdx.x;
  const int tid = threadIdx.x;
  __shared__ float p_s[64];

  const float* hrow = h + (size_t)bt*D_;
  const float* wrow = (tid < 32) ? (Wk + (size_t)tid*D_)
                                 : (Wq + (size_t)(tid-32)*D_);
  float dot = 0.f;
  for (int d = 0; d < D_; d += 4){
    float4 hv = ld4(&hrow[d]); float4 wv = ld4(&wrow[d]);
    dot += hv.x*wv.x + hv.y*wv.y + hv.z*wv.z + hv.w*wv.w;
  }
  float tau = (tid < 32) ? expf(ltw[0]) : expf(ltr[0]);
  float mx = dot;
#pragma unroll
  for (int m = 1; m < 16; m <<= 1) mx = fmaxf(mx, __shfl_xor(mx, m, 64));
  float e = expf((dot - mx)/tau);
  float sm = e;
#pragma unroll
  for (int m = 1; m < 16; m <<= 1) sm += __shfl_xor(sm, m, 64);
  p_s[tid] = e / sm;
  __syncthreads();

  const int half = tid >> 5;        // 0 = write stream, 1 = read stream
  const int l = tid & 31;
  const int g0 = half*32, g1 = half*32 + 16;
  float av[8];
#pragma unroll
  for (int k = 0; k < 8; ++k){
    int x = l*8 + k;
    av[k] = p_s[g0 + (x>>4)] * p_s[g1 + (x&15)];
  }
  const float sp = log1pf(expf(gammap[0]));
  for (int r = 0; r < TOPK_; ++r){
    float bv = -1.f; int bi = 0;
#pragma unroll
    for (int k = 0; k < 8; ++k){ if (av[k] > bv){ bv = av[k]; bi = l*8+k; } }
#pragma unroll
    for (int m = 1; m < 32; m <<= 1){
      float ov = __shfl_xor(bv, m, 64); int oi = __shfl_xor(bi, m, 64);
      if (ov > bv || (ov == bv && oi < bi)){ bv = ov; bi = oi; }
    }
    if ((bi >> 3) == l) av[bi & 7] = -2.f;
    if (tid == 0){
      widxb[bt*TOPK_+r] = bi; wwb[bt*TOPK_+r] = bv;
      decb[bt*TOPK_+r] = powf(1.f - bv, sp);
    }
    if (tid == 32) ridxb[bt*TOPK_+r] = bi;
  }
}

// ---------------------------------------------------------------------------
// A2: fp32 NT GEMM, 64x64 tile, batched over grid.z.
// ---------------------------------------------------------------------------
struct GemmPtrs { const float* W[6]; float* C[6]; };

__global__ __launch_bounds__(256) void gemm_nt(
    const float* __restrict__ A, GemmPtrs p)
{
  const float* W = p.W[blockIdx.z];
  float* C = p.C[blockIdx.z];
  const int n0 = blockIdx.x * 64;
  const int m0 = blockIdx.y * 64;
  const int tid = threadIdx.x;
  __shared__ __align__(16) float As[16][68];
  __shared__ __align__(16) float Bs[16][68];
  const int r  = tid >> 2;
  const int c4 = (tid & 3) << 2;
  const int tx4 = (tid & 15) << 2;
  const int ty4 = (tid >> 4) << 2;
  float acc[4][4] = {{0.f}};

  for (int kc = 0; kc < 512; kc += 16){
    float4 av = ld4(&A[(size_t)(m0+r)*512 + kc + c4]);
    float4 wv = ld4(&W[(size_t)(n0+r)*512 + kc + c4]);
    __syncthreads();
    As[c4+0][r]=av.x; As[c4+1][r]=av.y; As[c4+2][r]=av.z; As[c4+3][r]=av.w;
    Bs[c4+0][r]=wv.x; Bs[c4+1][r]=wv.y; Bs[c4+2][r]=wv.z; Bs[c4+3][r]=wv.w;
    __syncthreads();
#pragma unroll
    for (int k = 0; k < 16; ++k){
      float4 a  = ld4(&As[k][ty4]);
      float4 bq = ld4(&Bs[k][tx4]);
      acc[0][0]+=a.x*bq.x; acc[0][1]+=a.x*bq.y; acc[0][2]+=a.x*bq.z; acc[0][3]+=a.x*bq.w;
      acc[1][0]+=a.y*bq.x; acc[1][1]+=a.y*bq.y; acc[1][2]+=a.y*bq.z; acc[1][3]+=a.y*bq.w;
      acc[2][0]+=a.z*bq.x; acc[2][1]+=a.z*bq.y; acc[2][2]+=a.z*bq.z; acc[2][3]+=a.z*bq.w;
      acc[3][0]+=a.w*bq.x; acc[3][1]+=a.w*bq.y; acc[3][2]+=a.w*bq.z; acc[3][3]+=a.w*bq.w;
    }
  }
#pragma unroll
  for (int i = 0; i < 4; ++i){
    float4 cv; cv.x=acc[i][0]; cv.y=acc[i][1]; cv.z=acc[i][2]; cv.w=acc[i][3];
    st4(&C[(size_t)(m0+ty4+i)*512 + n0 + tx4], cv);
  }
}

// ---------------------------------------------------------------------------
// C: fused out = sigmoid(h@Wg.T) * (rdo@Wo.T).
// ---------------------------------------------------------------------------
__global__ __launch_bounds__(256) void gemm_out(
    const float* __restrict__ h, const float* __restrict__ rdo,
    const float* __restrict__ Wg, const float* __restrict__ Wo,
    float* __restrict__ C)
{
  const int n0 = blockIdx.x * 64;
  const int m0 = blockIdx.y * 64;
  const int tid = threadIdx.x;
  __shared__ __align__(16) float Ag[16][68];
  __shared__ __align__(16) float Ao[16][68];
  __shared__ __align__(16) float Bg[16][68];
  __shared__ __align__(16) float Bo[16][68];
  const int r  = tid >> 2;
  const int c4 = (tid & 3) << 2;
  const int tx4 = (tid & 15) << 2;
  const int ty4 = (tid >> 4) << 2;
  float accg[4][4] = {{0.f}};
  float acco[4][4] = {{0.f}};

  for (int kc = 0; kc < 512; kc += 16){
    float4 a1 = ld4(&h  [(size_t)(m0+r)*512 + kc + c4]);
    float4 a2 = ld4(&rdo[(size_t)(m0+r)*512 + kc + c4]);
    float4 w1 = ld4(&Wg [(size_t)(n0+r)*512 + kc + c4]);
    float4 w2 = ld4(&Wo [(size_t)(n0+r)*512 + kc + c4]);
    __syncthreads();
    Ag[c4+0][r]=a1.x; Ag[c4+1][r]=a1.y; Ag[c4+2][r]=a1.z; Ag[c4+3][r]=a1.w;
    Ao[c4+0][r]=a2.x; Ao[c4+1][r]=a2.y; Ao[c4+2][r]=a2.z; Ao[c4+3][r]=a2.w;
    Bg[c4+0][r]=w1.x; Bg[c4+1][r]=w1.y; Bg[c4+2][r]=w1.z; Bg[c4+3][r]=w1.w;
    Bo[c4+0][r]=w2.x; Bo[c4+1][r]=w2.y; Bo[c4+2][r]=w2.z; Bo[c4+3][r]=w2.w;
    __syncthreads();
#pragma unroll
    for (int k = 0; k < 16; ++k){
      float4 ag = ld4(&Ag[k][ty4]);
      float4 ao = ld4(&Ao[k][ty4]);
      float4 bg = ld4(&Bg[k][tx4]);
      float4 bo = ld4(&Bo[k][tx4]);
      accg[0][0]+=ag.x*bg.x; accg[0][1]+=ag.x*bg.y; accg[0][2]+=ag.x*bg.z; accg[0][3]+=ag.x*bg.w;
      accg[1][0]+=ag.y*bg.x; accg[1][1]+=ag.y*bg.y; accg[1][2]+=ag.y*bg.z; accg[1][3]+=ag.y*bg.w;
      accg[2][0]+=ag.z*bg.x; accg[2][1]+=ag.z*bg.y; accg[2][2]+=ag.z*bg.z; accg[2][3]+=ag.z*bg.w;
      accg[3][0]+=ag.w*bg.x; accg[3][1]+=ag.w*bg.y; accg[3][2]+=ag.w*bg.z; accg[3][3]+=ag.w*bg.w;
      acco[0][0]+=ao.x*bo.x; acco[0][1]+=ao.x*bo.y; acco[0][2]+=ao.x*bo.z; acco[0][3]+=ao.x*bo.w;
      acco[1][0]+=ao.y*bo.x; acco[1][1]+=ao.y*bo.y; acco[1][2]+=ao.y*bo.z; acco[1][3]+=ao.y*bo.w;
      acco[2][0]+=ao.z*bo.x; acco[2][1]+=ao.z*bo.y; acco[2][2]+=ao.z*bo.z; acco[2][3]+=ao.z*bo.w;
      acco[3][0]+=ao.w*bo.x; acco[3][1]+=ao.w*bo.y; acco[3][2]+=ao.w*bo.z; acco[3][3]+=ao.w*bo.w;
    }
  }
#pragma unroll
  for (int i = 0; i < 4; ++i){
    float4 cv;
    cv.x = acco[i][0] / (1.f + expf(-accg[i][0]));
    cv.y = acco[i][1] / (1.f + expf(-accg[i][1]));
    cv.z = acco[i][2] / (1.f + expf(-accg[i][2]));
    cv.w = acco[i][3] / (1.f + expf(-accg[i][3]));
    st4(&C[(size_t)(m0+ty4+i)*512 + n0 + tx4], cv);
  }
}

// ---------------------------------------------------------------------------
// A3: elementwise per (j, b, t): silu, row-norm -> k_hat, kv products, beta.
// ---------------------------------------------------------------------------
__global__ __launch_bounds__(256) void ew_kernel(
    float* __restrict__ khat, float* __restrict__ kvk, float* __restrict__ kvv,
    float* __restrict__ betab, const float* __restrict__ h,
    const float* __restrict__ hh_bw, const float* __restrict__ hh_bb)
{
  const int blk = blockIdx.x;
  const int j  = blk >> 10;
  const int bt = blk & 1023;
  const int tid = threadIdx.x;
  float* kp  = khat + (size_t)j*BT_*D_ + (size_t)bt*D_;
  float* vkp = kvk  + (size_t)j*BT_*D_ + (size_t)bt*D_;
  float* vvp = kvv  + (size_t)j*BT_*D_ + (size_t)bt*D_;
  const float* hp  = h + (size_t)bt*D_;
  const float* bwp = hh_bw + (size_t)j*D_;

  float s[2]; float nrm = 0.f, bd = 0.f;
#pragma unroll
  for (int q = 0; q < 2; ++q){
    int d = tid + q*256;
    float x = kp[d];
    float sv = x / (1.f + expf(-x));
    s[q] = sv; nrm += sv*sv; bd += hp[d]*bwp[d];
  }
  nrm = wred(nrm); bd = wred(bd);
  __shared__ float rb[8];
  int wid = tid >> 6, lane = tid & 63;
  if (lane == 0){ rb[wid] = nrm; rb[4+wid] = bd; }
  __syncthreads();
  float ns = rb[0]+rb[1]+rb[2]+rb[3];
  float bs = rb[4]+rb[5]+rb[6]+rb[7];
  float inv = 1.f / fmaxf(sqrtf(ns), 1e-12f);
#pragma unroll
  for (int q = 0; q < 2; ++q){
    int d = tid + q*256;
    float sv = s[q];
    kp[d]  = sv * inv;
    vkp[d] = sv * vkp[d];
    vvp[d] = sv * vvp[d];
  }
  if (tid == 0) betab[(size_t)j*BT_ + bt] = 2.f / (1.f + expf(-(bs + hh_bb[j])));
}

// ---------------------------------------------------------------------------
// A4: per-(b,t) cross-head scalars: c01 = k1.k0, dK = k1.u0K, dV = k1.u0V.
// ---------------------------------------------------------------------------
__global__ __launch_bounds__(64) void pre_kernel(
    const float* __restrict__ khat, const float* __restrict__ kvk,
    const float* __restrict__ kvv, float* __restrict__ preb)
{
  const int bt = blockIdx.x;
  const int lane = threadIdx.x;
  const float* k0 = khat + (size_t)bt*D_;
  const float* k1 = khat + (size_t)BT_*D_ + (size_t)bt*D_;
  const float* u0 = kvk + (size_t)bt*D_;
  const float* v0 = kvv + (size_t)bt*D_;
  float c = 0.f, dk = 0.f, dv = 0.f;
#pragma unroll
  for (int q = 0; q < 8; ++q){
    int d = lane*8 + q;
    float kv = k1[d];
    c += kv*k0[d]; dk += kv*u0[d]; dv += kv*v0[d];
  }
  c = wred(c); dk = wred(dk); dv = wred(dv);
  if (lane == 0){ preb[bt*4] = c; preb[bt*4+1] = dk; preb[bt*4+2] = dv; }
}

// ---------------------------------------------------------------------------
// B: sequential scan v3. 512 threads (8 waves); all staging in registers,
// one step ahead; state/read rows prefetched; fused 2-head update with one
// 4-way wred round; 2 barriers/step, the second a raw lgkm-only s_barrier
// so prefetch loads stay in flight across it.
// ---------------------------------------------------------------------------
__global__ __launch_bounds__(512, 2) void scan_kernel(
    float* __restrict__ Ks, float* __restrict__ Vs,
    const float* __restrict__ zK0, const float* __restrict__ zV0,
    const float* __restrict__ khat, const float* __restrict__ kvkb,
    const float* __restrict__ kvvb, const float* __restrict__ betab,
    const float* __restrict__ preb,
    const int* __restrict__ widxb, const float* __restrict__ wwb,
    const float* __restrict__ decb, const int* __restrict__ ridxb,
    const float* __restrict__ h, float* __restrict__ readout,
    float* __restrict__ o_zK, float* __restrict__ o_zV,
    float* __restrict__ o_widx, float* __restrict__ o_ridx)
{
  __shared__ __align__(16) float fwdK[TOPK_][D_];
  __shared__ __align__(16) float fwdV[TOPK_][D_];
  __shared__ __align__(16) float Vr_s[TOPK_][D_];
  __shared__ float zK_s[M_], zV_s[M_];
  __shared__ float rel_s[TOPK_], zvr_s[TOPK_];

  const int b = blockIdx.x;
  const int tid = threadIdx.x;
  const int s = tid >> 6, lane = tid & 63;
  const int l4 = lane * 4;
  const float scale = 0.044194173824159216f;   // 1/sqrt(512)

  float* Ksb = Ks + (size_t)b*M_*D_;
  float* Vsb = Vs + (size_t)b*M_*D_;
  const float* kh0p = khat;
  const float* kh1p = khat + (size_t)BT_*D_;
  const float* uk0p = kvkb;
  const float* uk1p = kvkb + (size_t)BT_*D_;
  const float* uv0p = kvvb;
  const float* uv1p = kvvb + (size_t)BT_*D_;

  // ---- prologue: idx for t=0,1; staged vectors t=0; state/read rows t=0 ----
  const int bt0 = b*T_;
  int   mi  = widxb[bt0*TOPK_ + s];
  float ww  = wwb [bt0*TOPK_ + s];
  float dec = decb[bt0*TOPK_ + s];
  int   ri  = ridxb[bt0*TOPK_ + s];
  int   wv8 = widxb[bt0*TOPK_ + (lane & 7)];
  float be0 = betab[bt0], be1 = betab[BT_ + bt0];
  float c01 = preb[bt0*4], dKp = preb[bt0*4+1], dVp = preb[bt0*4+2];

  const int bt1 = bt0 + 1;
  int   mi_n  = widxb[bt1*TOPK_ + s];
  float ww_n  = wwb [bt1*TOPK_ + s];
  float dec_n = decb[bt1*TOPK_ + s];
  int   ri_n  = ridxb[bt1*TOPK_ + s];
  int   wv8_n = widxb[bt1*TOPK_ + (lane & 7)];
  float be0_n = betab[bt1], be1_n = betab[BT_ + bt1];
  float c01_n = preb[bt1*4], dKp_n = preb[bt1*4+1], dVp_n = preb[bt1*4+2];

  size_t o0 = (size_t)bt0*D_ + l4;
  float4 sKH0a = ld4(kh0p+o0), sKH0b = ld4(kh0p+o0+256);
  float4 sKH1a = ld4(kh1p+o0), sKH1b = ld4(kh1p+o0+256);
  float4 sUK0a = ld4(uk0p+o0), sUK0b = ld4(uk0p+o0+256);
  float4 sUK1a = ld4(uk1p+o0), sUK1b = ld4(uk1p+o0+256);
  float4 sUV0a = ld4(uv0p+o0), sUV0b = ld4(uv0p+o0+256);
  float4 sUV1a = ld4(uv1p+o0), sUV1b = ld4(uv1p+o0+256);
  float4 sHTa  = ld4(h+o0),    sHTb  = ld4(h+o0+256);

  float4 K0 = ld4(&Ksb[(size_t)mi*D_ + l4]);
  float4 K1 = ld4(&Ksb[(size_t)mi*D_ + 256 + l4]);
  float4 V0 = ld4(&Vsb[(size_t)mi*D_ + l4]);
  float4 V1 = ld4(&Vsb[(size_t)mi*D_ + 256 + l4]);
  float4 RK0 = ld4(&Ksb[(size_t)ri*D_ + l4]);
  float4 RK1 = ld4(&Ksb[(size_t)ri*D_ + 256 + l4]);
  float4 RV0 = ld4(&Vsb[(size_t)ri*D_ + l4]);
  float4 RV1 = ld4(&Vsb[(size_t)ri*D_ + 256 + l4]);

  if (tid < M_){ zK_s[tid] = zK0[b*M_+tid]; zV_s[tid] = zV0[b*M_+tid]; }
  __syncthreads();

#pragma unroll 2
  for (int t = 0; t < T_; ++t){
    const int bt = b*T_ + t;

    // ---------------- P1 ----------------
    if (t > 0){
      // softmax + readout for step t-1
      float rl[TOPK_];
#pragma unroll
      for (int i = 0; i < TOPK_; ++i) rl[i] = rel_s[i];
      float mx = rl[0];
#pragma unroll
      for (int i = 1; i < TOPK_; ++i) mx = fmaxf(mx, rl[i]);
      float ev[TOPK_]; float smm = 0.f;
#pragma unroll
      for (int i = 0; i < TOPK_; ++i){ ev[i] = expf(rl[i]-mx); smm += ev[i]; }
      float inv = 1.f / smm;
      float r = 0.f;
#pragma unroll
      for (int i = 0; i < TOPK_; ++i) r += (ev[i]*inv/zvr_s[i]) * Vr_s[i][tid];
      readout[(size_t)(bt-1)*D_ + tid] = r;
    }

    // state update for t (rows prefetched; decayed here)
    K0 = scl4(K0,dec); K1 = scl4(K1,dec);
    V0 = scl4(V0,dec); V1 = scl4(V1,dec);
    float aK = dot4(K0,sKH0a) + dot4(K1,sKH0b);
    float bK = dot4(K0,sKH1a) + dot4(K1,sKH1b);
    float aV = dot4(V0,sKH0a) + dot4(V1,sKH0b);
    float bV = dot4(V0,sKH1a) + dot4(V1,sKH1b);
#pragma unroll
    for (int m = 1; m < 64; m <<= 1){
      aK += __shfl_xor(aK,m,64); bK += __shfl_xor(bK,m,64);
      aV += __shfl_xor(aV,m,64); bV += __shfl_xor(bV,m,64);
    }
    float s1K = bK + be0*(dKp - aK*c01);
    float s1V = bV + be0*(dVp - aV*c01);
    float p0K = be0*aK, p1K = be1*s1K;
    float p0V = be0*aV, p1V = be1*s1V;
    K0 = upd4(K0, sUK0a, sUK1a, sKH0a, sKH1a, be0, be1, p0K, p1K);
    K1 = upd4(K1, sUK0b, sUK1b, sKH0b, sKH1b, be0, be1, p0K, p1K);
    V0 = upd4(V0, sUV0a, sUV1a, sKH0a, sKH1a, be0, be1, p0V, p1V);
    V1 = upd4(V1, sUV0b, sUV1b, sKH0b, sKH1b, be0, be1, p0V, p1V);

    st4(&fwdK[s][l4], K0); st4(&fwdK[s][256+l4], K1);
    st4(&fwdV[s][l4], V0); st4(&fwdV[s][256+l4], V1);
    st4(&Ksb[(size_t)mi*D_ + l4], K0); st4(&Ksb[(size_t)mi*D_ + 256 + l4], K1);
    st4(&Vsb[(size_t)mi*D_ + l4], V0); st4(&Vsb[(size_t)mi*D_ + 256 + l4], V1);
    if (lane == 0)      zK_s[mi] = dec*zK_s[mi] + ww;
    else if (lane == 1) zV_s[mi] = dec*zV_s[mi] + ww;
    __syncthreads();   // b1: full drain — scatter visible, fwd/z visible

    // ---------------- P2 ----------------
    const int btn  = (t+1 < T_) ? bt+1 : bt;
    const int btnn = (t+2 < T_) ? bt+2 : btn;
    size_t on = (size_t)btn*D_ + l4;

    // staged vectors for t+1 (registers, in flight across raw barrier)
    float4 pKH0a = ld4(kh0p+on), pKH0b = ld4(kh0p+on+256);
    float4 pKH1a = ld4(kh1p+on), pKH1b = ld4(kh1p+on+256);
    float4 pUK0a = ld4(uk0p+on), pUK0b = ld4(uk0p+on+256);
    float4 pUK1a = ld4(uk1p+on), pUK1b = ld4(uk1p+on+256);
    float4 pUV0a = ld4(uv0p+on), pUV0b = ld4(uv0p+on+256);
    float4 pUV1a = ld4(uv1p+on), pUV1b = ld4(uv1p+on+256);
    float4 pHTa  = ld4(h+on),    pHTb  = ld4(h+on+256);
    // state + read row prefetch for t+1
    float4 nK0 = ld4(&Ksb[(size_t)mi_n*D_ + l4]);
    float4 nK1 = ld4(&Ksb[(size_t)mi_n*D_ + 256 + l4]);
    float4 nV0 = ld4(&Vsb[(size_t)mi_n*D_ + l4]);
    float4 nV1 = ld4(&Vsb[(size_t)mi_n*D_ + 256 + l4]);
    float4 nRK0 = ld4(&Ksb[(size_t)ri_n*D_ + l4]);
    float4 nRK1 = ld4(&Ksb[(size_t)ri_n*D_ + 256 + l4]);
    float4 nRV0 = ld4(&Vsb[(size_t)ri_n*D_ + l4]);
    float4 nRV1 = ld4(&Vsb[(size_t)ri_n*D_ + 256 + l4]);
    // idx pipeline for t+2
    int   mi_nn  = widxb[btnn*TOPK_ + s];
    float ww_nn  = wwb [btnn*TOPK_ + s];
    float dec_nn = decb[btnn*TOPK_ + s];
    int   ri_nn  = ridxb[btnn*TOPK_ + s];
    int   wv8_nn = widxb[btnn*TOPK_ + (lane & 7)];
    float be0_nn = betab[btnn], be1_nn = betab[BT_ + btnn];
    float c01_nn = preb[btnn*4], dKp_nn = preb[btnn*4+1], dVp_nn = preb[btnn*4+2];

    // read resolve for t: forwarded if ri in this step's write set
    unsigned long long mk = __ballot((lane < 8) && (wv8 == ri));
    float4 rk0, rk1, rv0, rv1;
    if (mk){
      int fm = __ffsll((unsigned long long)mk) - 1;
      rk0 = ld4(&fwdK[fm][l4]); rk1 = ld4(&fwdK[fm][256+l4]);
      rv0 = ld4(&fwdV[fm][l4]); rv1 = ld4(&fwdV[fm][256+l4]);
    } else {
      rk0 = RK0; rk1 = RK1; rv0 = RV0; rv1 = RV1;
    }
    float dt = dot4(rk0,sHTa) + dot4(rk1,sHTb);
    dt = wred(dt);
    st4(&Vr_s[s][l4], rv0); st4(&Vr_s[s][256+l4], rv1);
    if (lane == 0){
      rel_s[s] = dt * scale / zK_s[ri];
      zvr_s[s] = zV_s[ri];
    }

    // b2: raw barrier, lgkmcnt(0) only — prefetch loads stay in flight
    __builtin_amdgcn_s_waitcnt(0xc07f);
    __builtin_amdgcn_s_barrier();

    // rotate pipeline registers
    sKH0a=pKH0a; sKH0b=pKH0b; sKH1a=pKH1a; sKH1b=pKH1b;
    sUK0a=pUK0a; sUK0b=pUK0b; sUK1a=pUK1a; sUK1b=pUK1b;
    sUV0a=pUV0a; sUV0b=pUV0b; sUV1a=pUV1a; sUV1b=pUV1b;
    sHTa=pHTa; sHTb=pHTb;
    K0=nK0; K1=nK1; V0=nV0; V1=nV1;
    RK0=nRK0; RK1=nRK1; RV0=nRV0; RV1=nRV1;
    mi=mi_n; ww=ww_n; dec=dec_n; ri=ri_n; wv8=wv8_n;
    be0=be0_n; be1=be1_n; c01=c01_n; dKp=dKp_n; dVp=dVp_n;
    mi_n=mi_nn; ww_n=ww_nn; dec_n=dec_nn; ri_n=ri_nn; wv8_n=wv8_nn;
    be0_n=be0_nn; be1_n=be1_nn; c01_n=c01_nn; dKp_n=dKp_nn; dVp_n=dVp_nn;
  }

  // ---- epilogue: readout for t = T-1, final z and last-step indices ----
  {
    const int btL = b*T_ + T_ - 1;
    float rl[TOPK_];
#pragma unroll
    for (int i = 0; i < TOPK_; ++i) rl[i] = rel_s[i];
    float mx = rl[0];
#pragma unroll
    for (int i = 1; i < TOPK_; ++i) mx = fmaxf(mx, rl[i]);
    float ev[TOPK_]; float smm = 0.f;
#pragma unroll
    for (int i = 0; i < TOPK_; ++i){ ev[i] = expf(rl[i]-mx); smm += ev[i]; }
    float inv = 1.f / smm;
    float r = 0.f;
#pragma unroll
    for (int i = 0; i < TOPK_; ++i) r += (ev[i]*inv/zvr_s[i]) * Vr_s[i][tid];
    readout[(size_t)btL*D_ + tid] = r;

    if (tid < M_){ o_zK[b*M_+tid] = zK_s[tid]; o_zV[b*M_+tid] = zV_s[tid]; }
    if (tid < TOPK_){
      o_widx[b*TOPK_+tid] = (float)widxb[btL*TOPK_ + tid];
      o_ridx[b*TOPK_+tid] = (float)ridxb[btL*TOPK_ + tid];
    }
  }
}

// ---------------------------------------------------------------------------
extern "C" void kernel_launch(void* const* d_in, const int* in_sizes, int n_in,
                              void* d_out, int out_size, void* d_ws, size_t ws_size,
                              hipStream_t stream)
{
  (void)in_sizes; (void)n_in; (void)out_size; (void)ws_size;
  const float* h       = (const float*)d_in[0];
  const float* K_slots = (const float*)d_in[1];
  const float* V_slots = (const float*)d_in[2];
  const float* z_K     = (const float*)d_in[3];
  const float* z_V     = (const float*)d_in[4];
  const float* W_k     = (const float*)d_in[5];
  const float* W_q     = (const float*)d_in[6];
  const float* ltw     = (const float*)d_in[7];
  const float* ltr     = (const float*)d_in[8];
  const float* hh_k    = (const float*)d_in[9];
  const float* hh_vk   = (const float*)d_in[10];
  const float* hh_vv   = (const float*)d_in[11];
  const float* hh_bw   = (const float*)d_in[12];
  const float* hh_bb   = (const float*)d_in[13];
  const float* gamma   = (const float*)d_in[14];
  const float* W_out   = (const float*)d_in[15];
  const float* W_gate  = (const float*)d_in[16];

  float* out    = (float*)d_out;
  float* o_outs = out;                 // (B,T,D)   524288
  float* o_Ks   = out + 524288;        // (B,M,D)  1048576
  float* o_Vs   = out + 1572864;       // (B,M,D)  1048576
  float* o_zK   = out + 2621440;       // (B,M)       2048
  float* o_zV   = out + 2623488;       // (B,M)       2048
  float* o_widx = out + 2625536;       // (B,8)         64
  float* o_ridx = out + 2625600;       // (B,8)         64

  float* ws    = (float*)d_ws;
  float* khat  = ws;                         // 2 * BT * D
  float* kvk   = ws + 2*(size_t)BT_*D_;      // 2 * BT * D
  float* kvv   = kvk + 2*(size_t)BT_*D_;     // 2 * BT * D
  float* rdo   = kvv + 2*(size_t)BT_*D_;     // BT * D
  float* betab = rdo + (size_t)BT_*D_;       // 2 * BT
  float* wwb   = betab + 2*BT_;              // BT * 8
  float* decb  = wwb + BT_*TOPK_;            // BT * 8
  int*   widxb = (int*)(decb + BT_*TOPK_);   // BT * 8
  int*   ridxb = widxb + BT_*TOPK_;          // BT * 8
  float* preb  = (float*)(ridxb + BT_*TOPK_);// BT * 4

  hipMemcpyAsync(o_Ks, K_slots, sizeof(float)*(size_t)B_*M_*D_,
                 hipMemcpyDeviceToDevice, stream);
  hipMemcpyAsync(o_Vs, V_slots, sizeof(float)*(size_t)B_*M_*D_,
                 hipMemcpyDeviceToDevice, stream);

  addr_kernel<<<BT_, 64, 0, stream>>>(h, W_k, W_q, ltw, ltr, gamma,
                                      widxb, wwb, decb, ridxb);

  GemmPtrs p{};
  p.W[0] = hh_k;           p.C[0] = khat;
  p.W[1] = hh_k + 262144;  p.C[1] = khat + (size_t)BT_*D_;
  p.W[2] = hh_vk;          p.C[2] = kvk;
  p.W[3] = hh_vk + 262144; p.C[3] = kvk + (size_t)BT_*D_;
  p.W[4] = hh_vv;          p.C[4] = kvv;
  p.W[5] = hh_vv + 262144; p.C[5] = kvv + (size_t)BT_*D_;
  gemm_nt<<<dim3(8,16,6), 256, 0, stream>>>(h, p);

  ew_kernel<<<2*BT_, 256, 0, stream>>>(khat, kvk, kvv, betab, h, hh_bw, hh_bb);
  pre_kernel<<<BT_, 64, 0, stream>>>(khat, kvk, kvv, preb);

  scan_kernel<<<B_, 512, 0, stream>>>(o_Ks, o_Vs, z_K, z_V, khat, kvk, kvv,
                                      betab, preb, widxb, wwb, decb, ridxb,
                                      h, rdo, o_zK, o_zV, o_widx, o_ridx);

  gemm_out<<<dim3(8,16), 256, 0, stream>>>(h, rdo, W_gate, W_out, o_outs);
}

// Round 4
// 576.195 us; speedup vs baseline: 1.6923x; 1.2141x over previous
//
#include <hip/hip_runtime.h>
#include <math.h>

#define D_ 512
#define M_ 256
#define T_ 128
#define B_ 8
#define TOPK_ 8
#define NH_ 2
#define BT_ (B_*T_)

__device__ __forceinline__ float wred(float v){
#pragma unroll
  for (int m = 1; m < 64; m <<= 1) v += __shfl_xor(v, m, 64);
  return v;
}
__device__ __forceinline__ float4 ld4(const float* p){ return *(const float4*)p; }
__device__ __forceinline__ void st4(float* p, float4 v){ *(float4*)p = v; }
__device__ __forceinline__ float dot4(float4 a, float4 b){
  return a.x*b.x + a.y*b.y + a.z*b.z + a.w*b.w;
}
__device__ __forceinline__ float4 scl4(float4 a, float s){
  a.x*=s; a.y*=s; a.z*=s; a.w*=s; return a;
}
__device__ __forceinline__ float4 upd4(float4 r, float4 u0, float4 u1,
                                       float4 k0, float4 k1,
                                       float b0, float b1, float p0, float p1){
  r.x += b0*u0.x + b1*u1.x - p0*k0.x - p1*k1.x;
  r.y += b0*u0.y + b1*u1.y - p0*k0.y - p1*k1.y;
  r.z += b0*u0.z + b1*u1.z - p0*k0.z - p1*k1.z;
  r.w += b0*u0.w + b1*u1.w - p0*k0.w - p1*k1.w;
  return r;
}

// ---------------------------------------------------------------------------
// A1: addresses + parallel top-8.
// ---------------------------------------------------------------------------
__global__ __launch_bounds__(64) void addr_kernel(
    const float* __restrict__ h, const float* __restrict__ Wk,
    const float* __restrict__ Wq, const float* __restrict__ ltw,
    const float* __restrict__ ltr, const float* __restrict__ gammap,
    int* __restrict__ widxb, float* __restrict__ wwb,
    float* __restrict__ decb, int* __restrict__ ridxb)
{
  const int bt = blockIdx.x;
  const int tid = threadIdx.x;
  __shared__ float p_s[64];

  const float* hrow = h + (size_t)bt*D_;
  const float* wrow = (tid < 32) ? (Wk + (size_t)tid*D_)
                                 : (Wq + (size_t)(tid-32)*D_);
  float dot = 0.f;
  for (int d = 0; d < D_; d += 4){
    float4 hv = ld4(&hrow[d]); float4 wv = ld4(&wrow[d]);
    dot += hv.x*wv.x + hv.y*wv.y + hv.z*wv.z + hv.w*wv.w;
  }
  float tau = (tid < 32) ? expf(ltw[0]) : expf(ltr[0]);
  float mx = dot;
#pragma unroll
  for (int m = 1; m < 16; m <<= 1) mx = fmaxf(mx, __shfl_xor(mx, m, 64));
  float e = expf((dot - mx)/tau);
  float sm = e;
#pragma unroll
  for (int m = 1; m < 16; m <<= 1) sm += __shfl_xor(sm, m, 64);
  p_s[tid] = e / sm;
  __syncthreads();

  const int half = tid >> 5;
  const int l = tid & 31;
  const int g0 = half*32, g1 = half*32 + 16;
  float av[8];
#pragma unroll
  for (int k = 0; k < 8; ++k){
    int x = l*8 + k;
    av[k] = p_s[g0 + (x>>4)] * p_s[g1 + (x&15)];
  }
  const float sp = log1pf(expf(gammap[0]));
  for (int r = 0; r < TOPK_; ++r){
    float bv = -1.f; int bi = 0;
#pragma unroll
    for (int k = 0; k < 8; ++k){ if (av[k] > bv){ bv = av[k]; bi = l*8+k; } }
#pragma unroll
    for (int m = 1; m < 32; m <<= 1){
      float ov = __shfl_xor(bv, m, 64); int oi = __shfl_xor(bi, m, 64);
      if (ov > bv || (ov == bv && oi < bi)){ bv = ov; bi = oi; }
    }
    if ((bi >> 3) == l) av[bi & 7] = -2.f;
    if (tid == 0){
      widxb[bt*TOPK_+r] = bi; wwb[bt*TOPK_+r] = bv;
      decb[bt*TOPK_+r] = powf(1.f - bv, sp);
    }
    if (tid == 32) ridxb[bt*TOPK_+r] = bi;
  }
}

// ---------------------------------------------------------------------------
// A2: fp32 NT GEMM, 64x64 tile, batched over grid.z.
// ---------------------------------------------------------------------------
struct GemmPtrs { const float* W[6]; float* C[6]; };

__global__ __launch_bounds__(256) void gemm_nt(
    const float* __restrict__ A, GemmPtrs p)
{
  const float* W = p.W[blockIdx.z];
  float* C = p.C[blockIdx.z];
  const int n0 = blockIdx.x * 64;
  const int m0 = blockIdx.y * 64;
  const int tid = threadIdx.x;
  __shared__ __align__(16) float As[16][68];
  __shared__ __align__(16) float Bs[16][68];
  const int r  = tid >> 2;
  const int c4 = (tid & 3) << 2;
  const int tx4 = (tid & 15) << 2;
  const int ty4 = (tid >> 4) << 2;
  float acc[4][4] = {{0.f}};

  for (int kc = 0; kc < 512; kc += 16){
    float4 av = ld4(&A[(size_t)(m0+r)*512 + kc + c4]);
    float4 wv = ld4(&W[(size_t)(n0+r)*512 + kc + c4]);
    __syncthreads();
    As[c4+0][r]=av.x; As[c4+1][r]=av.y; As[c4+2][r]=av.z; As[c4+3][r]=av.w;
    Bs[c4+0][r]=wv.x; Bs[c4+1][r]=wv.y; Bs[c4+2][r]=wv.z; Bs[c4+3][r]=wv.w;
    __syncthreads();
#pragma unroll
    for (int k = 0; k < 16; ++k){
      float4 a  = ld4(&As[k][ty4]);
      float4 bq = ld4(&Bs[k][tx4]);
      acc[0][0]+=a.x*bq.x; acc[0][1]+=a.x*bq.y; acc[0][2]+=a.x*bq.z; acc[0][3]+=a.x*bq.w;
      acc[1][0]+=a.y*bq.x; acc[1][1]+=a.y*bq.y; acc[1][2]+=a.y*bq.z; acc[1][3]+=a.y*bq.w;
      acc[2][0]+=a.z*bq.x; acc[2][1]+=a.z*bq.y; acc[2][2]+=a.z*bq.z; acc[2][3]+=a.z*bq.w;
      acc[3][0]+=a.w*bq.x; acc[3][1]+=a.w*bq.y; acc[3][2]+=a.w*bq.z; acc[3][3]+=a.w*bq.w;
    }
  }
#pragma unroll
  for (int i = 0; i < 4; ++i){
    float4 cv; cv.x=acc[i][0]; cv.y=acc[i][1]; cv.z=acc[i][2]; cv.w=acc[i][3];
    st4(&C[(size_t)(m0+ty4+i)*512 + n0 + tx4], cv);
  }
}

// ---------------------------------------------------------------------------
// C: fused out = sigmoid(h@Wg.T) * (rdo@Wo.T).
// ---------------------------------------------------------------------------
__global__ __launch_bounds__(256) void gemm_out(
    const float* __restrict__ h, const float* __restrict__ rdo,
    const float* __restrict__ Wg, const float* __restrict__ Wo,
    float* __restrict__ C)
{
  const int n0 = blockIdx.x * 64;
  const int m0 = blockIdx.y * 64;
  const int tid = threadIdx.x;
  __shared__ __align__(16) float Ag[16][68];
  __shared__ __align__(16) float Ao[16][68];
  __shared__ __align__(16) float Bg[16][68];
  __shared__ __align__(16) float Bo[16][68];
  const int r  = tid >> 2;
  const int c4 = (tid & 3) << 2;
  const int tx4 = (tid & 15) << 2;
  const int ty4 = (tid >> 4) << 2;
  float accg[4][4] = {{0.f}};
  float acco[4][4] = {{0.f}};

  for (int kc = 0; kc < 512; kc += 16){
    float4 a1 = ld4(&h  [(size_t)(m0+r)*512 + kc + c4]);
    float4 a2 = ld4(&rdo[(size_t)(m0+r)*512 + kc + c4]);
    float4 w1 = ld4(&Wg [(size_t)(n0+r)*512 + kc + c4]);
    float4 w2 = ld4(&Wo [(size_t)(n0+r)*512 + kc + c4]);
    __syncthreads();
    Ag[c4+0][r]=a1.x; Ag[c4+1][r]=a1.y; Ag[c4+2][r]=a1.z; Ag[c4+3][r]=a1.w;
    Ao[c4+0][r]=a2.x; Ao[c4+1][r]=a2.y; Ao[c4+2][r]=a2.z; Ao[c4+3][r]=a2.w;
    Bg[c4+0][r]=w1.x; Bg[c4+1][r]=w1.y; Bg[c4+2][r]=w1.z; Bg[c4+3][r]=w1.w;
    Bo[c4+0][r]=w2.x; Bo[c4+1][r]=w2.y; Bo[c4+2][r]=w2.z; Bo[c4+3][r]=w2.w;
    __syncthreads();
#pragma unroll
    for (int k = 0; k < 16; ++k){
      float4 ag = ld4(&Ag[k][ty4]);
      float4 ao = ld4(&Ao[k][ty4]);
      float4 bg = ld4(&Bg[k][tx4]);
      float4 bo = ld4(&Bo[k][tx4]);
      accg[0][0]+=ag.x*bg.x; accg[0][1]+=ag.x*bg.y; accg[0][2]+=ag.x*bg.z; accg[0][3]+=ag.x*bg.w;
      accg[1][0]+=ag.y*bg.x; accg[1][1]+=ag.y*bg.y; accg[1][2]+=ag.y*bg.z; accg[1][3]+=ag.y*bg.w;
      accg[2][0]+=ag.z*bg.x; accg[2][1]+=ag.z*bg.y; accg[2][2]+=ag.z*bg.z; accg[2][3]+=ag.z*bg.w;
      accg[3][0]+=ag.w*bg.x; accg[3][1]+=ag.w*bg.y; accg[3][2]+=ag.w*bg.z; accg[3][3]+=ag.w*bg.w;
      acco[0][0]+=ao.x*bo.x; acco[0][1]+=ao.x*bo.y; acco[0][2]+=ao.x*bo.z; acco[0][3]+=ao.x*bo.w;
      acco[1][0]+=ao.y*bo.x; acco[1][1]+=ao.y*bo.y; acco[1][2]+=ao.y*bo.z; acco[1][3]+=ao.y*bo.w;
      acco[2][0]+=ao.z*bo.x; acco[2][1]+=ao.z*bo.y; acco[2][2]+=ao.z*bo.z; acco[2][3]+=ao.z*bo.w;
      acco[3][0]+=ao.w*bo.x; acco[3][1]+=ao.w*bo.y; acco[3][2]+=ao.w*bo.z; acco[3][3]+=ao.w*bo.w;
    }
  }
#pragma unroll
  for (int i = 0; i < 4; ++i){
    float4 cv;
    cv.x = acco[i][0] / (1.f + expf(-accg[i][0]));
    cv.y = acco[i][1] / (1.f + expf(-accg[i][1]));
    cv.z = acco[i][2] / (1.f + expf(-accg[i][2]));
    cv.w = acco[i][3] / (1.f + expf(-accg[i][3]));
    st4(&C[(size_t)(m0+ty4+i)*512 + n0 + tx4], cv);
  }
}

// ---------------------------------------------------------------------------
// A3: elementwise per (j, b, t): silu, row-norm -> k_hat, kv products, beta.
// ---------------------------------------------------------------------------
__global__ __launch_bounds__(256) void ew_kernel(
    float* __restrict__ khat, float* __restrict__ kvk, float* __restrict__ kvv,
    float* __restrict__ betab, const float* __restrict__ h,
    const float* __restrict__ hh_bw, const float* __restrict__ hh_bb)
{
  const int blk = blockIdx.x;
  const int j  = blk >> 10;
  const int bt = blk & 1023;
  const int tid = threadIdx.x;
  float* kp  = khat + (size_t)j*BT_*D_ + (size_t)bt*D_;
  float* vkp = kvk  + (size_t)j*BT_*D_ + (size_t)bt*D_;
  float* vvp = kvv  + (size_t)j*BT_*D_ + (size_t)bt*D_;
  const float* hp  = h + (size_t)bt*D_;
  const float* bwp = hh_bw + (size_t)j*D_;

  float s[2]; float nrm = 0.f, bd = 0.f;
#pragma unroll
  for (int q = 0; q < 2; ++q){
    int d = tid + q*256;
    float x = kp[d];
    float sv = x / (1.f + expf(-x));
    s[q] = sv; nrm += sv*sv; bd += hp[d]*bwp[d];
  }
  nrm = wred(nrm); bd = wred(bd);
  __shared__ float rb[8];
  int wid = tid >> 6, lane = tid & 63;
  if (lane == 0){ rb[wid] = nrm; rb[4+wid] = bd; }
  __syncthreads();
  float ns = rb[0]+rb[1]+rb[2]+rb[3];
  float bs = rb[4]+rb[5]+rb[6]+rb[7];
  float inv = 1.f / fmaxf(sqrtf(ns), 1e-12f);
#pragma unroll
  for (int q = 0; q < 2; ++q){
    int d = tid + q*256;
    float sv = s[q];
    kp[d]  = sv * inv;
    vkp[d] = sv * vkp[d];
    vvp[d] = sv * vvp[d];
  }
  if (tid == 0) betab[(size_t)j*BT_ + bt] = 2.f / (1.f + expf(-(bs + hh_bb[j])));
}

// ---------------------------------------------------------------------------
// A4: per-(b,t) cross-head scalars: c01 = k1.k0, dK = k1.u0K, dV = k1.u0V.
// ---------------------------------------------------------------------------
__global__ __launch_bounds__(64) void pre_kernel(
    const float* __restrict__ khat, const float* __restrict__ kvk,
    const float* __restrict__ kvv, float* __restrict__ preb)
{
  const int bt = blockIdx.x;
  const int lane = threadIdx.x;
  const float* k0 = khat + (size_t)bt*D_;
  const float* k1 = khat + (size_t)BT_*D_ + (size_t)bt*D_;
  const float* u0 = kvk + (size_t)bt*D_;
  const float* v0 = kvv + (size_t)bt*D_;
  float c = 0.f, dk = 0.f, dv = 0.f;
#pragma unroll
  for (int q = 0; q < 8; ++q){
    int d = lane*8 + q;
    float kv = k1[d];
    c += kv*k0[d]; dk += kv*u0[d]; dv += kv*v0[d];
  }
  c = wred(c); dk = wred(dk); dv = wred(dv);
  if (lane == 0){ preb[bt*4] = c; preb[bt*4+1] = dk; preb[bt*4+2] = dv; }
}

// ---------------------------------------------------------------------------
// B: sequential scan v4. 512 threads (8 waves). Staged vectors go through a
// 3-slot LDS ring, single-copy: each wave loads 1-2 float4 chunks for step
// t+3 in P2(t) (registers), ds_writes them into the ring one step later —
// the vmcnt wait lands a full step after issue. State/read rows prefetched
// in registers (small pressure, pipeline survives). b1 full sync (drains
// ~5 store-acks), b2 lgkm-only so global loads fly across it.
// ---------------------------------------------------------------------------
__global__ __launch_bounds__(512, 2) void scan_kernel(
    float* __restrict__ Ks, float* __restrict__ Vs,
    const float* __restrict__ zK0, const float* __restrict__ zV0,
    const float* __restrict__ khat, const float* __restrict__ kvkb,
    const float* __restrict__ kvvb, const float* __restrict__ betab,
    const float* __restrict__ preb,
    const int* __restrict__ widxb, const float* __restrict__ wwb,
    const float* __restrict__ decb, const int* __restrict__ ridxb,
    const float* __restrict__ h, float* __restrict__ readout,
    float* __restrict__ o_zK, float* __restrict__ o_zV,
    float* __restrict__ o_widx, float* __restrict__ o_ridx)
{
  __shared__ __align__(16) float ring[3][7*D_];
  __shared__ __align__(16) float fwdK[TOPK_][D_];
  __shared__ __align__(16) float fwdV[TOPK_][D_];
  __shared__ __align__(16) float Vr_s[TOPK_][D_];
  __shared__ float zK_s[M_], zV_s[M_];
  __shared__ float rel_s[TOPK_], zvr_s[TOPK_];

  const int b = blockIdx.x;
  const int tid = threadIdx.x;
  const int s = tid >> 6, lane = tid & 63;
  const int l4 = lane * 4;
  const float scale = 0.044194173824159216f;   // 1/sqrt(512)

  float* Ksb = Ks + (size_t)b*M_*D_;
  float* Vsb = Vs + (size_t)b*M_*D_;
  const float* vb[7] = { khat, khat + (size_t)BT_*D_,
                         kvkb, kvkb + (size_t)BT_*D_,
                         kvvb, kvvb + (size_t)BT_*D_, h };

  // chunk assignment: 14 chunks (7 vectors x 2 halves); wave s gets chunks
  // c0 = s and c1 = s+8 (c1 valid for s < 6).
  const int c0 = s, c1 = s + 8;
  const bool has1 = (c1 < 14);
  const float* src0 = vb[c0 >> 1];
  const float* src1 = vb[has1 ? (c1 >> 1) : 0];
  const int goff0 = (c0 & 1)*256 + l4;
  const int goff1 = (c1 & 1)*256 + l4;
  const int loff0 = (c0 >> 1)*D_ + goff0;
  const int loff1 = has1 ? ((c1 >> 1)*D_ + goff1) : 0;

  // ---- prologue ----
  const int bt0 = b*T_;
  // stage t=0,1 directly; issue loads for t=2 into registers
  for (int tt = 0; tt < 2; ++tt){
    float4 a = ld4(src0 + (size_t)(bt0+tt)*D_ + goff0);
    st4(&ring[tt][loff0], a);
    if (has1){
      float4 c = ld4(src1 + (size_t)(bt0+tt)*D_ + goff1);
      st4(&ring[tt][loff1], c);
    }
  }
  float4 g0 = ld4(src0 + (size_t)(bt0+2)*D_ + goff0);
  float4 g1 = has1 ? ld4(src1 + (size_t)(bt0+2)*D_ + goff1)
                   : make_float4(0.f,0.f,0.f,0.f);

  // scalar pipeline t=0, t=1
  int   mi  = widxb[bt0*TOPK_ + s];
  float ww  = wwb [bt0*TOPK_ + s];
  float dec = decb[bt0*TOPK_ + s];
  int   ri  = ridxb[bt0*TOPK_ + s];
  int   wv8 = widxb[bt0*TOPK_ + (lane & 7)];
  float be0 = betab[bt0], be1 = betab[BT_ + bt0];
  float c01 = preb[bt0*4], dKp = preb[bt0*4+1], dVp = preb[bt0*4+2];

  const int bt1 = bt0 + 1;
  int   mi_n  = widxb[bt1*TOPK_ + s];
  float ww_n  = wwb [bt1*TOPK_ + s];
  float dec_n = decb[bt1*TOPK_ + s];
  int   ri_n  = ridxb[bt1*TOPK_ + s];
  int   wv8_n = widxb[bt1*TOPK_ + (lane & 7)];
  float be0_n = betab[bt1], be1_n = betab[BT_ + bt1];
  float c01_n = preb[bt1*4], dKp_n = preb[bt1*4+1], dVp_n = preb[bt1*4+2];

  // state + read rows for t=0
  float4 K0 = ld4(&Ksb[(size_t)mi*D_ + l4]);
  float4 K1 = ld4(&Ksb[(size_t)mi*D_ + 256 + l4]);
  float4 V0 = ld4(&Vsb[(size_t)mi*D_ + l4]);
  float4 V1 = ld4(&Vsb[(size_t)mi*D_ + 256 + l4]);
  float4 RK0 = ld4(&Ksb[(size_t)ri*D_ + l4]);
  float4 RK1 = ld4(&Ksb[(size_t)ri*D_ + 256 + l4]);
  float4 RV0 = ld4(&Vsb[(size_t)ri*D_ + l4]);
  float4 RV1 = ld4(&Vsb[(size_t)ri*D_ + 256 + l4]);

  if (tid < M_){ zK_s[tid] = zK0[b*M_+tid]; zV_s[tid] = zV0[b*M_+tid]; }
  __syncthreads();

#pragma unroll 2
  for (int t = 0; t < T_; ++t){
    const int bt = b*T_ + t;
    const float* rbuf = ring[t % 3];

    // ---------------- P1 ----------------
    // staged slices from the ring
    float4 sKH0a = ld4(&rbuf[l4]),        sKH0b = ld4(&rbuf[256+l4]);
    float4 sKH1a = ld4(&rbuf[D_+l4]),     sKH1b = ld4(&rbuf[D_+256+l4]);
    float4 sUK0a = ld4(&rbuf[2*D_+l4]),   sUK0b = ld4(&rbuf[2*D_+256+l4]);
    float4 sUK1a = ld4(&rbuf[3*D_+l4]),   sUK1b = ld4(&rbuf[3*D_+256+l4]);
    float4 sUV0a = ld4(&rbuf[4*D_+l4]),   sUV0b = ld4(&rbuf[4*D_+256+l4]);
    float4 sUV1a = ld4(&rbuf[5*D_+l4]),   sUV1b = ld4(&rbuf[5*D_+256+l4]);
    float4 sHTa  = ld4(&rbuf[6*D_+l4]),   sHTb  = ld4(&rbuf[6*D_+256+l4]);

    if (t > 0){
      // softmax + readout for step t-1 (fast exp, reciprocal-z pre-stored)
      float rl[TOPK_];
#pragma unroll
      for (int i = 0; i < TOPK_; ++i) rl[i] = rel_s[i];
      float mx = rl[0];
#pragma unroll
      for (int i = 1; i < TOPK_; ++i) mx = fmaxf(mx, rl[i]);
      float smm = 0.f, r = 0.f;
#pragma unroll
      for (int i = 0; i < TOPK_; ++i){
        float ev = __expf(rl[i]-mx); smm += ev;
        r += ev * zvr_s[i] * Vr_s[i][tid];
      }
      readout[(size_t)(bt-1)*D_ + tid] = r / smm;
    }

    // fused 2-head state update
    K0 = scl4(K0,dec); K1 = scl4(K1,dec);
    V0 = scl4(V0,dec); V1 = scl4(V1,dec);
    float aK = dot4(K0,sKH0a) + dot4(K1,sKH0b);
    float bK = dot4(K0,sKH1a) + dot4(K1,sKH1b);
    float aV = dot4(V0,sKH0a) + dot4(V1,sKH0b);
    float bV = dot4(V0,sKH1a) + dot4(V1,sKH1b);
#pragma unroll
    for (int m = 1; m < 64; m <<= 1){
      aK += __shfl_xor(aK,m,64); bK += __shfl_xor(bK,m,64);
      aV += __shfl_xor(aV,m,64); bV += __shfl_xor(bV,m,64);
    }
    float s1K = bK + be0*(dKp - aK*c01);
    float s1V = bV + be0*(dVp - aV*c01);
    float p0K = be0*aK, p1K = be1*s1K;
    float p0V = be0*aV, p1V = be1*s1V;
    K0 = upd4(K0, sUK0a, sUK1a, sKH0a, sKH1a, be0, be1, p0K, p1K);
    K1 = upd4(K1, sUK0b, sUK1b, sKH0b, sKH1b, be0, be1, p0K, p1K);
    V0 = upd4(V0, sUV0a, sUV1a, sKH0a, sKH1a, be0, be1, p0V, p1V);
    V1 = upd4(V1, sUV0b, sUV1b, sKH0b, sKH1b, be0, be1, p0V, p1V);

    st4(&fwdK[s][l4], K0); st4(&fwdK[s][256+l4], K1);
    st4(&fwdV[s][l4], V0); st4(&fwdV[s][256+l4], V1);
    st4(&Ksb[(size_t)mi*D_ + l4], K0); st4(&Ksb[(size_t)mi*D_ + 256 + l4], K1);
    st4(&Vsb[(size_t)mi*D_ + l4], V0); st4(&Vsb[(size_t)mi*D_ + 256 + l4], V1);
    if (lane == 0)      zK_s[mi] = dec*zK_s[mi] + ww;
    else if (lane == 1) zV_s[mi] = dec*zV_s[mi] + ww;
    __syncthreads();   // b1: scatter visible, fwd/z visible

    // ---------------- P2 ----------------
    // commit staged chunks for t+2 (loaded in P2 of t-1; long since arrived)
    float* wbuf = ring[(t+2) % 3];
    st4(&wbuf[loff0], g0);
    if (has1) st4(&wbuf[loff1], g1);
    // issue staging loads for t+3
    const int bt3 = (t+3 < T_) ? bt+3 : b*T_+T_-1;
    g0 = ld4(src0 + (size_t)bt3*D_ + goff0);
    if (has1) g1 = ld4(src1 + (size_t)bt3*D_ + goff1);

    // state + read row prefetch for t+1 (after b1: sees this step's scatter)
    float4 nK0 = ld4(&Ksb[(size_t)mi_n*D_ + l4]);
    float4 nK1 = ld4(&Ksb[(size_t)mi_n*D_ + 256 + l4]);
    float4 nV0 = ld4(&Vsb[(size_t)mi_n*D_ + l4]);
    float4 nV1 = ld4(&Vsb[(size_t)mi_n*D_ + 256 + l4]);
    float4 nRK0 = ld4(&Ksb[(size_t)ri_n*D_ + l4]);
    float4 nRK1 = ld4(&Ksb[(size_t)ri_n*D_ + 256 + l4]);
    float4 nRV0 = ld4(&Vsb[(size_t)ri_n*D_ + l4]);
    float4 nRV1 = ld4(&Vsb[(size_t)ri_n*D_ + 256 + l4]);

    // scalar pipeline for t+2
    const int btnn = (t+2 < T_) ? bt+2 : b*T_+T_-1;
    int   mi_nn  = widxb[btnn*TOPK_ + s];
    float ww_nn  = wwb [btnn*TOPK_ + s];
    float dec_nn = decb[btnn*TOPK_ + s];
    int   ri_nn  = ridxb[btnn*TOPK_ + s];
    int   wv8_nn = widxb[btnn*TOPK_ + (lane & 7)];
    float be0_nn = betab[btnn], be1_nn = betab[BT_ + btnn];
    float c01_nn = preb[btnn*4], dKp_nn = preb[btnn*4+1], dVp_nn = preb[btnn*4+2];

    // read resolve for t: forwarded if ri in this step's write set
    unsigned long long mk = __ballot((lane < 8) && (wv8 == ri));
    float4 rk0, rk1, rv0, rv1;
    if (mk){
      int fm = __ffsll(mk) - 1;
      rk0 = ld4(&fwdK[fm][l4]); rk1 = ld4(&fwdK[fm][256+l4]);
      rv0 = ld4(&fwdV[fm][l4]); rv1 = ld4(&fwdV[fm][256+l4]);
    } else {
      rk0 = RK0; rk1 = RK1; rv0 = RV0; rv1 = RV1;
    }
    float dt = dot4(rk0,sHTa) + dot4(rk1,sHTb);
    dt = wred(dt);
    st4(&Vr_s[s][l4], rv0); st4(&Vr_s[s][256+l4], rv1);
    if (lane == 0){
      rel_s[s] = dt * scale / zK_s[ri];
      zvr_s[s] = 1.0f / zV_s[ri];
    }

    // b2: raw barrier, lgkmcnt(0) only — global loads stay in flight
    __builtin_amdgcn_s_waitcnt(0xc07f);
    __builtin_amdgcn_s_barrier();

    // rotate pipeline
    K0=nK0; K1=nK1; V0=nV0; V1=nV1;
    RK0=nRK0; RK1=nRK1; RV0=nRV0; RV1=nRV1;
    mi=mi_n; ww=ww_n; dec=dec_n; ri=ri_n; wv8=wv8_n;
    be0=be0_n; be1=be1_n; c01=c01_n; dKp=dKp_n; dVp=dVp_n;
    mi_n=mi_nn; ww_n=ww_nn; dec_n=dec_nn; ri_n=ri_nn; wv8_n=wv8_nn;
    be0_n=be0_nn; be1_n=be1_nn; c01_n=c01_nn; dKp_n=dKp_nn; dVp_n=dVp_nn;
  }

  // ---- epilogue: readout for t = T-1, final z and last-step indices ----
  {
    const int btL = b*T_ + T_ - 1;
    float rl[TOPK_];
#pragma unroll
    for (int i = 0; i < TOPK_; ++i) rl[i] = rel_s[i];
    float mx = rl[0];
#pragma unroll
    for (int i = 1; i < TOPK_; ++i) mx = fmaxf(mx, rl[i]);
    float smm = 0.f, r = 0.f;
#pragma unroll
    for (int i = 0; i < TOPK_; ++i){
      float ev = __expf(rl[i]-mx); smm += ev;
      r += ev * zvr_s[i] * Vr_s[i][tid];
    }
    readout[(size_t)btL*D_ + tid] = r / smm;

    if (tid < M_){ o_zK[b*M_+tid] = zK_s[tid]; o_zV[b*M_+tid] = zV_s[tid]; }
    if (tid < TOPK_){
      o_widx[b*TOPK_+tid] = (float)widxb[btL*TOPK_ + tid];
      o_ridx[b*TOPK_+tid] = (float)ridxb[btL*TOPK_ + tid];
    }
  }
}

// ---------------------------------------------------------------------------
extern "C" void kernel_launch(void* const* d_in, const int* in_sizes, int n_in,
                              void* d_out, int out_size, void* d_ws, size_t ws_size,
                              hipStream_t stream)
{
  (void)in_sizes; (void)n_in; (void)out_size; (void)ws_size;
  const float* h       = (const float*)d_in[0];
  const float* K_slots = (const float*)d_in[1];
  const float* V_slots = (const float*)d_in[2];
  const float* z_K     = (const float*)d_in[3];
  const float* z_V     = (const float*)d_in[4];
  const float* W_k     = (const float*)d_in[5];
  const float* W_q     = (const float*)d_in[6];
  const float* ltw     = (const float*)d_in[7];
  const float* ltr     = (const float*)d_in[8];
  const float* hh_k    = (const float*)d_in[9];
  const float* hh_vk   = (const float*)d_in[10];
  const float* hh_vv   = (const float*)d_in[11];
  const float* hh_bw   = (const float*)d_in[12];
  const float* hh_bb   = (const float*)d_in[13];
  const float* gamma   = (const float*)d_in[14];
  const float* W_out   = (const float*)d_in[15];
  const float* W_gate  = (const float*)d_in[16];

  float* out    = (float*)d_out;
  float* o_outs = out;                 // (B,T,D)   524288
  float* o_Ks   = out + 524288;        // (B,M,D)  1048576
  float* o_Vs   = out + 1572864;       // (B,M,D)  1048576
  float* o_zK   = out + 2621440;       // (B,M)       2048
  float* o_zV   = out + 2623488;       // (B,M)       2048
  float* o_widx = out + 2625536;       // (B,8)         64
  float* o_ridx = out + 2625600;       // (B,8)         64

  float* ws    = (float*)d_ws;
  float* khat  = ws;                         // 2 * BT * D
  float* kvk   = ws + 2*(size_t)BT_*D_;      // 2 * BT * D
  float* kvv   = kvk + 2*(size_t)BT_*D_;     // 2 * BT * D
  float* rdo   = kvv + 2*(size_t)BT_*D_;     // BT * D
  float* betab = rdo + (size_t)BT_*D_;       // 2 * BT
  float* wwb   = betab + 2*BT_;              // BT * 8
  float* decb  = wwb + BT_*TOPK_;            // BT * 8
  int*   widxb = (int*)(decb + BT_*TOPK_);   // BT * 8
  int*   ridxb = widxb + BT_*TOPK_;          // BT * 8
  float* preb  = (float*)(ridxb + BT_*TOPK_);// BT * 4

  hipMemcpyAsync(o_Ks, K_slots, sizeof(float)*(size_t)B_*M_*D_,
                 hipMemcpyDeviceToDevice, stream);
  hipMemcpyAsync(o_Vs, V_slots, sizeof(float)*(size_t)B_*M_*D_,
                 hipMemcpyDeviceToDevice, stream);

  addr_kernel<<<BT_, 64, 0, stream>>>(h, W_k, W_q, ltw, ltr, gamma,
                                      widxb, wwb, decb, ridxb);

  GemmPtrs p{};
  p.W[0] = hh_k;           p.C[0] = khat;
  p.W[1] = hh_k + 262144;  p.C[1] = khat + (size_t)BT_*D_;
  p.W[2] = hh_vk;          p.C[2] = kvk;
  p.W[3] = hh_vk + 262144; p.C[3] = kvk + (size_t)BT_*D_;
  p.W[4] = hh_vv;          p.C[4] = kvv;
  p.W[5] = hh_vv + 262144; p.C[5] = kvv + (size_t)BT_*D_;
  gemm_nt<<<dim3(8,16,6), 256, 0, stream>>>(h, p);

  ew_kernel<<<2*BT_, 256, 0, stream>>>(khat, kvk, kvv, betab, h, hh_bw, hh_bb);
  pre_kernel<<<BT_, 64, 0, stream>>>(khat, kvk, kvv, preb);

  scan_kernel<<<B_, 512, 0, stream>>>(o_Ks, o_Vs, z_K, z_V, khat, kvk, kvv,
                                      betab, preb, widxb, wwb, decb, ridxb,
                                      h, rdo, o_zK, o_zV, o_widx, o_ridx);

  gemm_out<<<dim3(8,16), 256, 0, stream>>>(h, rdo, W_gate, W_out, o_outs);
}

// Round 6
// 510.474 us; speedup vs baseline: 1.9102x; 1.1287x over previous
//
#include <hip/hip_runtime.h>
#include <math.h>

#define D_ 512
#define M_ 256
#define T_ 128
#define B_ 8
#define TOPK_ 8
#define NH_ 2
#define BT_ (B_*T_)

__device__ __forceinline__ float wred(float v){
#pragma unroll
  for (int m = 1; m < 64; m <<= 1) v += __shfl_xor(v, m, 64);
  return v;
}
__device__ __forceinline__ float4 ld4(const float* p){ return *(const float4*)p; }
__device__ __forceinline__ void st4(float* p, float4 v){ *(float4*)p = v; }
__device__ __forceinline__ float dot4(float4 a, float4 b){
  return a.x*b.x + a.y*b.y + a.z*b.z + a.w*b.w;
}
__device__ __forceinline__ float4 scl4(float4 a, float s){
  a.x*=s; a.y*=s; a.z*=s; a.w*=s; return a;
}

// DPP wave64 sum: row_shr 1/2/4/8 + row_bcast15 + row_bcast31, result in
// lane 63, broadcast via readlane. VALU-pipe only — no DS traffic.
// dpp_ctrl must be an integer-constant expression -> template parameter.
template<int CTRL>
__device__ __forceinline__ float dpp_add(float x){
  int y = __builtin_amdgcn_update_dpp(0, __float_as_int(x), CTRL, 0xf, 0xf, true);
  return x + __int_as_float(y);
}
__device__ __forceinline__ float wredd(float x){
  x = dpp_add<0x111>(x);   // row_shr:1
  x = dpp_add<0x112>(x);   // row_shr:2
  x = dpp_add<0x114>(x);   // row_shr:4
  x = dpp_add<0x118>(x);   // row_shr:8
  x = dpp_add<0x142>(x);   // row_bcast:15
  x = dpp_add<0x143>(x);   // row_bcast:31
  return __int_as_float(__builtin_amdgcn_readlane(__float_as_int(x), 63));
}

__device__ __forceinline__ void bar_lgkm(){
  asm volatile("s_waitcnt lgkmcnt(0)\n\ts_barrier" ::: "memory");
}

// ---------------------------------------------------------------------------
// A1: addresses + parallel top-8. meta[bt][r] = {widx, ww, dec, ridx}.
// ---------------------------------------------------------------------------
__global__ __launch_bounds__(64) void addr_kernel(
    const float* __restrict__ h, const float* __restrict__ Wk,
    const float* __restrict__ Wq, const float* __restrict__ ltw,
    const float* __restrict__ ltr, const float* __restrict__ gammap,
    float* __restrict__ metab)
{
  const int bt = blockIdx.x;
  const int tid = threadIdx.x;
  __shared__ float p_s[64];

  const float* hrow = h + (size_t)bt*D_;
  const float* wrow = (tid < 32) ? (Wk + (size_t)tid*D_)
                                 : (Wq + (size_t)(tid-32)*D_);
  float dot = 0.f;
  for (int d = 0; d < D_; d += 4){
    float4 hv = ld4(&hrow[d]); float4 wv = ld4(&wrow[d]);
    dot += hv.x*wv.x + hv.y*wv.y + hv.z*wv.z + hv.w*wv.w;
  }
  float tau = (tid < 32) ? expf(ltw[0]) : expf(ltr[0]);
  float mx = dot;
#pragma unroll
  for (int m = 1; m < 16; m <<= 1) mx = fmaxf(mx, __shfl_xor(mx, m, 64));
  float e = expf((dot - mx)/tau);
  float sm = e;
#pragma unroll
  for (int m = 1; m < 16; m <<= 1) sm += __shfl_xor(sm, m, 64);
  p_s[tid] = e / sm;
  __syncthreads();

  const int half = tid >> 5;
  const int l = tid & 31;
  const int g0 = half*32, g1 = half*32 + 16;
  float av[8];
#pragma unroll
  for (int k = 0; k < 8; ++k){
    int x = l*8 + k;
    av[k] = p_s[g0 + (x>>4)] * p_s[g1 + (x&15)];
  }
  const float sp = log1pf(expf(gammap[0]));
  for (int r = 0; r < TOPK_; ++r){
    float bv = -1.f; int bi = 0;
#pragma unroll
    for (int k = 0; k < 8; ++k){ if (av[k] > bv){ bv = av[k]; bi = l*8+k; } }
#pragma unroll
    for (int m = 1; m < 32; m <<= 1){
      float ov = __shfl_xor(bv, m, 64); int oi = __shfl_xor(bi, m, 64);
      if (ov > bv || (ov == bv && oi < bi)){ bv = ov; bi = oi; }
    }
    if ((bi >> 3) == l) av[bi & 7] = -2.f;
    float* mp = metab + (size_t)(bt*TOPK_ + r)*4;
    if (tid == 0){
      mp[0] = __int_as_float(bi); mp[1] = bv; mp[2] = powf(1.f - bv, sp);
    }
    if (tid == 32) mp[3] = __int_as_float(bi);
  }
}

// ---------------------------------------------------------------------------
// A2: fp32 NT GEMM, 64x64 tile, batched over grid.z.
// ---------------------------------------------------------------------------
struct GemmPtrs { const float* W[6]; float* C[6]; };

__global__ __launch_bounds__(256) void gemm_nt(
    const float* __restrict__ A, GemmPtrs p)
{
  const float* W = p.W[blockIdx.z];
  float* C = p.C[blockIdx.z];
  const int n0 = blockIdx.x * 64;
  const int m0 = blockIdx.y * 64;
  const int tid = threadIdx.x;
  __shared__ __align__(16) float As[16][68];
  __shared__ __align__(16) float Bs[16][68];
  const int r  = tid >> 2;
  const int c4 = (tid & 3) << 2;
  const int tx4 = (tid & 15) << 2;
  const int ty4 = (tid >> 4) << 2;
  float acc[4][4] = {{0.f}};

  for (int kc = 0; kc < 512; kc += 16){
    float4 av = ld4(&A[(size_t)(m0+r)*512 + kc + c4]);
    float4 wv = ld4(&W[(size_t)(n0+r)*512 + kc + c4]);
    __syncthreads();
    As[c4+0][r]=av.x; As[c4+1][r]=av.y; As[c4+2][r]=av.z; As[c4+3][r]=av.w;
    Bs[c4+0][r]=wv.x; Bs[c4+1][r]=wv.y; Bs[c4+2][r]=wv.z; Bs[c4+3][r]=wv.w;
    __syncthreads();
#pragma unroll
    for (int k = 0; k < 16; ++k){
      float4 a  = ld4(&As[k][ty4]);
      float4 bq = ld4(&Bs[k][tx4]);
      acc[0][0]+=a.x*bq.x; acc[0][1]+=a.x*bq.y; acc[0][2]+=a.x*bq.z; acc[0][3]+=a.x*bq.w;
      acc[1][0]+=a.y*bq.x; acc[1][1]+=a.y*bq.y; acc[1][2]+=a.y*bq.z; acc[1][3]+=a.y*bq.w;
      acc[2][0]+=a.z*bq.x; acc[2][1]+=a.z*bq.y; acc[2][2]+=a.z*bq.z; acc[2][3]+=a.z*bq.w;
      acc[3][0]+=a.w*bq.x; acc[3][1]+=a.w*bq.y; acc[3][2]+=a.w*bq.z; acc[3][3]+=a.w*bq.w;
    }
  }
#pragma unroll
  for (int i = 0; i < 4; ++i){
    float4 cv; cv.x=acc[i][0]; cv.y=acc[i][1]; cv.z=acc[i][2]; cv.w=acc[i][3];
    st4(&C[(size_t)(m0+ty4+i)*512 + n0 + tx4], cv);
  }
}

// ---------------------------------------------------------------------------
// C: fused out = sigmoid(h@Wg.T) * (rdo@Wo.T).
// ---------------------------------------------------------------------------
__global__ __launch_bounds__(256) void gemm_out(
    const float* __restrict__ h, const float* __restrict__ rdo,
    const float* __restrict__ Wg, const float* __restrict__ Wo,
    float* __restrict__ C)
{
  const int n0 = blockIdx.x * 64;
  const int m0 = blockIdx.y * 64;
  const int tid = threadIdx.x;
  __shared__ __align__(16) float Ag[16][68];
  __shared__ __align__(16) float Ao[16][68];
  __shared__ __align__(16) float Bg[16][68];
  __shared__ __align__(16) float Bo[16][68];
  const int r  = tid >> 2;
  const int c4 = (tid & 3) << 2;
  const int tx4 = (tid & 15) << 2;
  const int ty4 = (tid >> 4) << 2;
  float accg[4][4] = {{0.f}};
  float acco[4][4] = {{0.f}};

  for (int kc = 0; kc < 512; kc += 16){
    float4 a1 = ld4(&h  [(size_t)(m0+r)*512 + kc + c4]);
    float4 a2 = ld4(&rdo[(size_t)(m0+r)*512 + kc + c4]);
    float4 w1 = ld4(&Wg [(size_t)(n0+r)*512 + kc + c4]);
    float4 w2 = ld4(&Wo [(size_t)(n0+r)*512 + kc + c4]);
    __syncthreads();
    Ag[c4+0][r]=a1.x; Ag[c4+1][r]=a1.y; Ag[c4+2][r]=a1.z; Ag[c4+3][r]=a1.w;
    Ao[c4+0][r]=a2.x; Ao[c4+1][r]=a2.y; Ao[c4+2][r]=a2.z; Ao[c4+3][r]=a2.w;
    Bg[c4+0][r]=w1.x; Bg[c4+1][r]=w1.y; Bg[c4+2][r]=w1.z; Bg[c4+3][r]=w1.w;
    Bo[c4+0][r]=w2.x; Bo[c4+1][r]=w2.y; Bo[c4+2][r]=w2.z; Bo[c4+3][r]=w2.w;
    __syncthreads();
#pragma unroll
    for (int k = 0; k < 16; ++k){
      float4 ag = ld4(&Ag[k][ty4]);
      float4 ao = ld4(&Ao[k][ty4]);
      float4 bg = ld4(&Bg[k][tx4]);
      float4 bo = ld4(&Bo[k][tx4]);
      accg[0][0]+=ag.x*bg.x; accg[0][1]+=ag.x*bg.y; accg[0][2]+=ag.x*bg.z; accg[0][3]+=ag.x*bg.w;
      accg[1][0]+=ag.y*bg.x; accg[1][1]+=ag.y*bg.y; accg[1][2]+=ag.y*bg.z; accg[1][3]+=ag.y*bg.w;
      accg[2][0]+=ag.z*bg.x; accg[2][1]+=ag.z*bg.y; accg[2][2]+=ag.z*bg.z; accg[2][3]+=ag.z*bg.w;
      accg[3][0]+=ag.w*bg.x; accg[3][1]+=ag.w*bg.y; accg[3][2]+=ag.w*bg.z; accg[3][3]+=ag.w*bg.w;
      acco[0][0]+=ao.x*bo.x; acco[0][1]+=ao.x*bo.y; acco[0][2]+=ao.x*bo.z; acco[0][3]+=ao.x*bo.w;
      acco[1][0]+=ao.y*bo.x; acco[1][1]+=ao.y*bo.y; acco[1][2]+=ao.y*bo.z; acco[1][3]+=ao.y*bo.w;
      acco[2][0]+=ao.z*bo.x; acco[2][1]+=ao.z*bo.y; acco[2][2]+=ao.z*bo.z; acco[2][3]+=ao.z*bo.w;
      acco[3][0]+=ao.w*bo.x; acco[3][1]+=ao.w*bo.y; acco[3][2]+=ao.w*bo.z; acco[3][3]+=ao.w*bo.w;
    }
  }
#pragma unroll
  for (int i = 0; i < 4; ++i){
    float4 cv;
    cv.x = acco[i][0] / (1.f + expf(-accg[i][0]));
    cv.y = acco[i][1] / (1.f + expf(-accg[i][1]));
    cv.z = acco[i][2] / (1.f + expf(-accg[i][2]));
    cv.w = acco[i][3] / (1.f + expf(-accg[i][3]));
    st4(&C[(size_t)(m0+ty4+i)*512 + n0 + tx4], cv);
  }
}

// ---------------------------------------------------------------------------
// A3: fused per-bt elementwise + cross-head precompute.
// Produces: khat (normalized), kvk0 <- ucK = be0*u0K + be1*u1K,
// kvv0 <- ucV, pre2[bt*8+{0..4}] = {c01, dK, dV, be0, be1}.
// ---------------------------------------------------------------------------
__global__ __launch_bounds__(256) void ew2_kernel(
    float* __restrict__ khat, float* __restrict__ kvk, float* __restrict__ kvv,
    float* __restrict__ pre2, const float* __restrict__ h,
    const float* __restrict__ hh_bw, const float* __restrict__ hh_bb)
{
  const int bt = blockIdx.x;
  const int tid = threadIdx.x;
  const int wid = tid >> 6, lane = tid & 63;
  float* k0p  = khat + (size_t)bt*D_;
  float* k1p  = khat + (size_t)BT_*D_ + (size_t)bt*D_;
  float* vk0p = kvk  + (size_t)bt*D_;
  float* vk1p = kvk  + (size_t)BT_*D_ + (size_t)bt*D_;
  float* vv0p = kvv  + (size_t)bt*D_;
  float* vv1p = kvv  + (size_t)BT_*D_ + (size_t)bt*D_;
  const float* hp  = h + (size_t)bt*D_;

  float s0[2], s1[2];
  float n0 = 0.f, n1 = 0.f, bd0 = 0.f, bd1 = 0.f;
#pragma unroll
  for (int q = 0; q < 2; ++q){
    int d = tid + q*256;
    float x0 = k0p[d], x1 = k1p[d], hv = hp[d];
    float v0 = x0 / (1.f + expf(-x0));
    float v1 = x1 / (1.f + expf(-x1));
    s0[q] = v0; s1[q] = v1;
    n0 += v0*v0; n1 += v1*v1;
    bd0 += hv*hh_bw[d]; bd1 += hv*hh_bw[D_ + d];
  }
  __shared__ float4 rb[4];
  float4 acc = make_float4(wred(n0), wred(n1), wred(bd0), wred(bd1));
  if (lane == 0) rb[wid] = acc;
  __syncthreads();
  float4 t0 = rb[0], t1 = rb[1], t2 = rb[2], t3 = rb[3];
  n0 = t0.x+t1.x+t2.x+t3.x; n1 = t0.y+t1.y+t2.y+t3.y;
  bd0 = t0.z+t1.z+t2.z+t3.z; bd1 = t0.w+t1.w+t2.w+t3.w;
  float inv0 = 1.f / fmaxf(sqrtf(n0), 1e-12f);
  float inv1 = 1.f / fmaxf(sqrtf(n1), 1e-12f);
  float be0 = 2.f / (1.f + expf(-(bd0 + hh_bb[0])));
  float be1 = 2.f / (1.f + expf(-(bd1 + hh_bb[1])));

  float c01 = 0.f, dK = 0.f, dV = 0.f;
#pragma unroll
  for (int q = 0; q < 2; ++q){
    int d = tid + q*256;
    float kh0 = s0[q]*inv0, kh1 = s1[q]*inv1;
    float u0K = s0[q]*vk0p[d], u1K = s1[q]*vk1p[d];
    float u0V = s0[q]*vv0p[d], u1V = s1[q]*vv1p[d];
    k0p[d] = kh0; k1p[d] = kh1;
    vk0p[d] = be0*u0K + be1*u1K;
    vv0p[d] = be0*u0V + be1*u1V;
    c01 += kh1*kh0; dK += kh1*u0K; dV += kh1*u0V;
  }
  __syncthreads();
  float4 acc2 = make_float4(wred(c01), wred(dK), wred(dV), 0.f);
  if (lane == 0) rb[wid] = acc2;
  __syncthreads();
  if (tid == 0){
    float4 a = rb[0], b = rb[1], c = rb[2], d = rb[3];
    pre2[(size_t)bt*8+0] = a.x+b.x+c.x+d.x;
    pre2[(size_t)bt*8+1] = a.y+b.y+c.y+d.y;
    pre2[(size_t)bt*8+2] = a.z+b.z+c.z+d.z;
    pre2[(size_t)bt*8+3] = be0;
    pre2[(size_t)bt*8+4] = be1;
  }
}

// ---------------------------------------------------------------------------
// B: sequential scan v5. 8 waves; DPP reductions (no DS shuffles); 4-vector
// LDS ring (kh0,kh1,ucK,ucV); ht via global; fwd writes conditional;
// b1 lgkm-only (scatter visibility handled via fwd-patch), b2 full sync.
// ---------------------------------------------------------------------------
__global__ __launch_bounds__(512, 2) void scan_kernel(
    float* __restrict__ Ks, float* __restrict__ Vs,
    const float* __restrict__ zK0, const float* __restrict__ zV0,
    const float* __restrict__ khat, const float* __restrict__ ucKb,
    const float* __restrict__ ucVb, const float* __restrict__ pre2,
    const float* __restrict__ metab, const float* __restrict__ h,
    float* __restrict__ readout,
    float* __restrict__ o_zK, float* __restrict__ o_zV,
    float* __restrict__ o_widx, float* __restrict__ o_ridx)
{
  __shared__ __align__(16) float ring[3][4*D_];
  __shared__ __align__(16) float fwdK[TOPK_][D_];
  __shared__ __align__(16) float fwdV[TOPK_][D_];
  __shared__ __align__(16) float Vr_s[TOPK_][D_];
  __shared__ float zK_s[M_], zV_s[M_];
  __shared__ float2 rel2_s[TOPK_];

  const int b = blockIdx.x;
  const int tid = threadIdx.x;
  const int s = tid >> 6, lane = tid & 63;
  const int l4 = lane * 4;
  const float scale = 0.044194173824159216f;   // 1/sqrt(512)

  float* Ksb = Ks + (size_t)b*M_*D_;
  float* Vsb = Vs + (size_t)b*M_*D_;
  const float* vbt[4] = { khat, khat + (size_t)BT_*D_, ucKb, ucVb };
  const float* srcc = vbt[s >> 1];
  const int goff = (s & 1)*256 + l4;
  const int loff = (s >> 1)*D_ + goff;
  const float4* mb = (const float4*)metab;

  // ---- prologue ----
  const int bt0 = b*T_;
  for (int tt = 0; tt < 2; ++tt)
    st4(&ring[tt][loff], ld4(srcc + (size_t)(bt0+tt)*D_ + goff));
  float4 g = ld4(srcc + (size_t)(bt0+2)*D_ + goff);

  float4 me   = mb[bt0*TOPK_ + s];
  float4 me8  = mb[bt0*TOPK_ + (lane & 7)];
  int   mi  = __float_as_int(me.x);  float ww  = me.y;  float dec = me.z;
  int   ri  = __float_as_int(me.w);
  int   wv8 = __float_as_int(me8.x); int rv8 = __float_as_int(me8.w);
  float4 pm = *(const float4*)&pre2[(size_t)bt0*8];
  float be1v = pre2[(size_t)bt0*8+4];
  float c01 = pm.x, dKp = pm.y, dVp = pm.z, be0 = pm.w;

  const int bt1 = bt0 + 1;
  float4 me_n  = mb[bt1*TOPK_ + s];
  float4 me8_n = mb[bt1*TOPK_ + (lane & 7)];
  int   mi_n  = __float_as_int(me_n.x);  float ww_n = me_n.y;
  float dec_n = me_n.z;                  int ri_n  = __float_as_int(me_n.w);
  int   wv8_n = __float_as_int(me8_n.x); int rv8_n = __float_as_int(me8_n.w);
  float4 pm_n = *(const float4*)&pre2[(size_t)bt1*8];
  float be1_n = pre2[(size_t)bt1*8+4];

  float4 K0 = ld4(&Ksb[(size_t)mi*D_ + l4]);
  float4 K1 = ld4(&Ksb[(size_t)mi*D_ + 256 + l4]);
  float4 V0 = ld4(&Vsb[(size_t)mi*D_ + l4]);
  float4 V1 = ld4(&Vsb[(size_t)mi*D_ + 256 + l4]);
  float4 RK0 = ld4(&Ksb[(size_t)ri*D_ + l4]);
  float4 RK1 = ld4(&Ksb[(size_t)ri*D_ + 256 + l4]);
  float4 RV0 = ld4(&Vsb[(size_t)ri*D_ + l4]);
  float4 RV1 = ld4(&Vsb[(size_t)ri*D_ + 256 + l4]);

  if (tid < M_){ zK_s[tid] = zK0[b*M_+tid]; zV_s[tid] = zV0[b*M_+tid]; }
  __syncthreads();

  for (int t = 0; t < T_; ++t){
    const int bt = b*T_ + t;
    const float* rbuf = ring[t % 3];

    // ---------------- P1 ----------------
    // ht for this step's P2 read-dot (global L2; used ~600 cyc later)
    float4 HTa = ld4(h + (size_t)bt*D_ + l4);
    float4 HTb = ld4(h + (size_t)bt*D_ + 256 + l4);

    // staged vectors from the ring
    float4 kh0a = ld4(&rbuf[l4]),        kh0b = ld4(&rbuf[256+l4]);
    float4 kh1a = ld4(&rbuf[D_+l4]),     kh1b = ld4(&rbuf[D_+256+l4]);
    float4 ucKa = ld4(&rbuf[2*D_+l4]),   ucKb2 = ld4(&rbuf[2*D_+256+l4]);
    float4 ucVa = ld4(&rbuf[3*D_+l4]),   ucVb2 = ld4(&rbuf[3*D_+256+l4]);

    if (t > 0){
      // softmax + readout for step t-1
      float2 rz[TOPK_];
#pragma unroll
      for (int i = 0; i < TOPK_; ++i) rz[i] = rel2_s[i];
      float mx = rz[0].x;
#pragma unroll
      for (int i = 1; i < TOPK_; ++i) mx = fmaxf(mx, rz[i].x);
      float smm = 0.f, r = 0.f;
#pragma unroll
      for (int i = 0; i < TOPK_; ++i){
        float ev = __expf(rz[i].x - mx); smm += ev;
        r += ev * rz[i].y * Vr_s[i][tid];
      }
      readout[(size_t)(bt-1)*D_ + tid] = r / smm;
    }

    // fused 2-head state update (DPP reductions)
    K0 = scl4(K0,dec); K1 = scl4(K1,dec);
    V0 = scl4(V0,dec); V1 = scl4(V1,dec);
    float aK = wredd(dot4(K0,kh0a) + dot4(K1,kh0b));
    float bK = wredd(dot4(K0,kh1a) + dot4(K1,kh1b));
    float aV = wredd(dot4(V0,kh0a) + dot4(V1,kh0b));
    float bV = wredd(dot4(V0,kh1a) + dot4(V1,kh1b));
    float p0K = be0*aK, p1K = be1v*(bK + be0*(dKp - aK*c01));
    float p0V = be0*aV, p1V = be1v*(bV + be0*(dVp - aV*c01));
    K0.x += ucKa.x  - p0K*kh0a.x - p1K*kh1a.x;
    K0.y += ucKa.y  - p0K*kh0a.y - p1K*kh1a.y;
    K0.z += ucKa.z  - p0K*kh0a.z - p1K*kh1a.z;
    K0.w += ucKa.w  - p0K*kh0a.w - p1K*kh1a.w;
    K1.x += ucKb2.x - p0K*kh0b.x - p1K*kh1b.x;
    K1.y += ucKb2.y - p0K*kh0b.y - p1K*kh1b.y;
    K1.z += ucKb2.z - p0K*kh0b.z - p1K*kh1b.z;
    K1.w += ucKb2.w - p0K*kh0b.w - p1K*kh1b.w;
    V0.x += ucVa.x  - p0V*kh0a.x - p1V*kh1a.x;
    V0.y += ucVa.y  - p0V*kh0a.y - p1V*kh1a.y;
    V0.z += ucVa.z  - p0V*kh0a.z - p1V*kh1a.z;
    V0.w += ucVa.w  - p0V*kh0a.w - p1V*kh1a.w;
    V1.x += ucVb2.x - p0V*kh0b.x - p1V*kh1b.x;
    V1.y += ucVb2.y - p0V*kh0b.y - p1V*kh1b.y;
    V1.z += ucVb2.z - p0V*kh0b.z - p1V*kh1b.z;
    V1.w += ucVb2.w - p0V*kh0b.w - p1V*kh1b.w;

    // conditional forward: only if my slot is needed by a patch/read
    unsigned long long nf =
        __ballot((lane < 8) && (rv8   == mi)) |
        __ballot((lane < 8) && (wv8_n == mi)) |
        __ballot((lane < 8) && (rv8_n == mi));
    if (nf){
      st4(&fwdK[s][l4], K0); st4(&fwdK[s][256+l4], K1);
      st4(&fwdV[s][l4], V0); st4(&fwdV[s][256+l4], V1);
    }
    // scatter (visibility deferred; patched via fwd this step, drained at b2)
    st4(&Ksb[(size_t)mi*D_ + l4], K0); st4(&Ksb[(size_t)mi*D_ + 256 + l4], K1);
    st4(&Vsb[(size_t)mi*D_ + l4], V0); st4(&Vsb[(size_t)mi*D_ + 256 + l4], V1);
    if (lane == 0)      zK_s[mi] = dec*zK_s[mi] + ww;
    else if (lane == 1) zV_s[mi] = dec*zV_s[mi] + ww;

    bar_lgkm();   // b1: fwd/z visible (LDS only)

    // ---------------- P2 ----------------
    // ring commit for t+2, issue fill load for t+3
    st4(&ring[(t+2)%3][loff], g);
    const int bt3 = (t+3 < T_) ? bt+3 : b*T_+T_-1;
    g = ld4(srcc + (size_t)bt3*D_ + goff);

    // state prefetch for t+1 (patched against write-set(t))
    unsigned long long hS = __ballot((lane < 8) && (wv8 == mi_n));
    float4 nK0, nK1, nV0, nV1;
    if (hS){
      int w = __ffsll(hS) - 1;
      nK0 = ld4(&fwdK[w][l4]); nK1 = ld4(&fwdK[w][256+l4]);
      nV0 = ld4(&fwdV[w][l4]); nV1 = ld4(&fwdV[w][256+l4]);
    } else {
      nK0 = ld4(&Ksb[(size_t)mi_n*D_ + l4]);
      nK1 = ld4(&Ksb[(size_t)mi_n*D_ + 256 + l4]);
      nV0 = ld4(&Vsb[(size_t)mi_n*D_ + l4]);
      nV1 = ld4(&Vsb[(size_t)mi_n*D_ + 256 + l4]);
    }
    // read-row prefetch for t+1 (patched likewise)
    unsigned long long hR = __ballot((lane < 8) && (wv8 == ri_n));
    float4 nRK0, nRK1, nRV0, nRV1;
    if (hR){
      int w = __ffsll(hR) - 1;
      nRK0 = ld4(&fwdK[w][l4]); nRK1 = ld4(&fwdK[w][256+l4]);
      nRV0 = ld4(&fwdV[w][l4]); nRV1 = ld4(&fwdV[w][256+l4]);
    } else {
      nRK0 = ld4(&Ksb[(size_t)ri_n*D_ + l4]);
      nRK1 = ld4(&Ksb[(size_t)ri_n*D_ + 256 + l4]);
      nRV0 = ld4(&Vsb[(size_t)ri_n*D_ + l4]);
      nRV1 = ld4(&Vsb[(size_t)ri_n*D_ + 256 + l4]);
    }

    // scalar pipeline for t+2
    const int btnn = (t+2 < T_) ? bt+2 : b*T_+T_-1;
    float4 me_nn  = mb[btnn*TOPK_ + s];
    float4 me8_nn = mb[btnn*TOPK_ + (lane & 7)];
    float4 pm_nn  = *(const float4*)&pre2[(size_t)btnn*8];
    float  be1_nn = pre2[(size_t)btnn*8+4];

    // read resolution for t
    unsigned long long mk = __ballot((lane < 8) && (wv8 == ri));
    float4 rk0, rk1, rv0, rv1;
    if (mk){
      int fm = __ffsll(mk) - 1;
      rk0 = ld4(&fwdK[fm][l4]); rk1 = ld4(&fwdK[fm][256+l4]);
      rv0 = ld4(&fwdV[fm][l4]); rv1 = ld4(&fwdV[fm][256+l4]);
    } else {
      rk0 = RK0; rk1 = RK1; rv0 = RV0; rv1 = RV1;
    }
    float dt = wredd(dot4(rk0,HTa) + dot4(rk1,HTb));
    st4(&Vr_s[s][l4], rv0); st4(&Vr_s[s][256+l4], rv1);
    if (lane == 0)
      rel2_s[s] = make_float2(dt * scale / zK_s[ri], 1.0f / zV_s[ri]);

    __syncthreads();  // b2: full drain — scatter stores complete, LDS visible

    // rotate pipeline
    K0=nK0; K1=nK1; V0=nV0; V1=nV1;
    RK0=nRK0; RK1=nRK1; RV0=nRV0; RV1=nRV1;
    mi=mi_n; ww=ww_n; dec=dec_n; ri=ri_n; wv8=wv8_n; rv8=rv8_n;
    c01=pm_n.x; dKp=pm_n.y; dVp=pm_n.z; be0=pm_n.w; be1v=be1_n;
    mi_n=__float_as_int(me_nn.x); ww_n=me_nn.y; dec_n=me_nn.z;
    ri_n=__float_as_int(me_nn.w);
    wv8_n=__float_as_int(me8_nn.x); rv8_n=__float_as_int(me8_nn.w);
    pm_n=pm_nn; be1_n=be1_nn;
  }

  // ---- epilogue: readout(T-1), final z, last-step indices ----
  {
    const int btL = b*T_ + T_ - 1;
    float2 rz[TOPK_];
#pragma unroll
    for (int i = 0; i < TOPK_; ++i) rz[i] = rel2_s[i];
    float mx = rz[0].x;
#pragma unroll
    for (int i = 1; i < TOPK_; ++i) mx = fmaxf(mx, rz[i].x);
    float smm = 0.f, r = 0.f;
#pragma unroll
    for (int i = 0; i < TOPK_; ++i){
      float ev = __expf(rz[i].x - mx); smm += ev;
      r += ev * rz[i].y * Vr_s[i][tid];
    }
    readout[(size_t)btL*D_ + tid] = r / smm;

    if (tid < M_){ o_zK[b*M_+tid] = zK_s[tid]; o_zV[b*M_+tid] = zV_s[tid]; }
    if (tid < TOPK_){
      float4 m = mb[btL*TOPK_ + tid];
      o_widx[b*TOPK_+tid] = (float)__float_as_int(m.x);
      o_ridx[b*TOPK_+tid] = (float)__float_as_int(m.w);
    }
  }
}

// ---------------------------------------------------------------------------
extern "C" void kernel_launch(void* const* d_in, const int* in_sizes, int n_in,
                              void* d_out, int out_size, void* d_ws, size_t ws_size,
                              hipStream_t stream)
{
  (void)in_sizes; (void)n_in; (void)out_size; (void)ws_size;
  const float* h       = (const float*)d_in[0];
  const float* K_slots = (const float*)d_in[1];
  const float* V_slots = (const float*)d_in[2];
  const float* z_K     = (const float*)d_in[3];
  const float* z_V     = (const float*)d_in[4];
  const float* W_k     = (const float*)d_in[5];
  const float* W_q     = (const float*)d_in[6];
  const float* ltw     = (const float*)d_in[7];
  const float* ltr     = (const float*)d_in[8];
  const float* hh_k    = (const float*)d_in[9];
  const float* hh_vk   = (const float*)d_in[10];
  const float* hh_vv   = (const float*)d_in[11];
  const float* hh_bw   = (const float*)d_in[12];
  const float* hh_bb   = (const float*)d_in[13];
  const float* gamma   = (const float*)d_in[14];
  const float* W_out   = (const float*)d_in[15];
  const float* W_gate  = (const float*)d_in[16];

  float* out    = (float*)d_out;
  float* o_outs = out;                 // (B,T,D)   524288
  float* o_Ks   = out + 524288;        // (B,M,D)  1048576
  float* o_Vs   = out + 1572864;       // (B,M,D)  1048576
  float* o_zK   = out + 2621440;       // (B,M)       2048
  float* o_zV   = out + 2623488;       // (B,M)       2048
  float* o_widx = out + 2625536;       // (B,8)         64
  float* o_ridx = out + 2625600;       // (B,8)         64

  float* ws    = (float*)d_ws;
  float* khat  = ws;                          // 2 * BT * D
  float* kvk   = ws + 2*(size_t)BT_*D_;       // 2 * BT * D
  float* kvv   = kvk + 2*(size_t)BT_*D_;      // 2 * BT * D
  float* rdo   = kvv + 2*(size_t)BT_*D_;      // BT * D
  float* metab = rdo + (size_t)BT_*D_;        // BT * 8 * 4
  float* pre2  = metab + (size_t)BT_*TOPK_*4; // BT * 8

  (void)hipMemcpyAsync(o_Ks, K_slots, sizeof(float)*(size_t)B_*M_*D_,
                       hipMemcpyDeviceToDevice, stream);
  (void)hipMemcpyAsync(o_Vs, V_slots, sizeof(float)*(size_t)B_*M_*D_,
                       hipMemcpyDeviceToDevice, stream);

  addr_kernel<<<BT_, 64, 0, stream>>>(h, W_k, W_q, ltw, ltr, gamma, metab);

  GemmPtrs p{};
  p.W[0] = hh_k;           p.C[0] = khat;
  p.W[1] = hh_k + 262144;  p.C[1] = khat + (size_t)BT_*D_;
  p.W[2] = hh_vk;          p.C[2] = kvk;
  p.W[3] = hh_vk + 262144; p.C[3] = kvk + (size_t)BT_*D_;
  p.W[4] = hh_vv;          p.C[4] = kvv;
  p.W[5] = hh_vv + 262144; p.C[5] = kvv + (size_t)BT_*D_;
  gemm_nt<<<dim3(8,16,6), 256, 0, stream>>>(h, p);

  ew2_kernel<<<BT_, 256, 0, stream>>>(khat, kvk, kvv, pre2, h, hh_bw, hh_bb);

  scan_kernel<<<B_, 512, 0, stream>>>(o_Ks, o_Vs, z_K, z_V, khat, kvk, kvv,
                                      pre2, metab, h, rdo,
                                      o_zK, o_zV, o_widx, o_ridx);

  gemm_out<<<dim3(8,16), 256, 0, stream>>>(h, rdo, W_gate, W_out, o_outs);
}